// Round 5
// baseline (2675.784 us; speedup 1.0000x reference)
//
#include <hip/hip_runtime.h>
#include <hip/hip_bf16.h>

// ChebNet classifier: 3x ChebConv(K=6) + pool + linear. fp32 internal.
// Round 5: CSR scatter rewritten as two-phase binned sort:
//   pass A appends packed (rowlow,col) to per-bucket regions (offsets free from
//   the CSR scan), 8 planes by blockIdx&7 to keep tail lines XCD-local;
//   pass B sorts each 256-row bucket into exact CSR order in LDS and writes
//   colS fully coalesced. Kills the 396MB/15x write amplification of round 4.

#define N0 200000
#define N1 50000
#define N2 12500
#define KCH 6
#define NCLS 10

#define SB 8                 // bucket = 256 rows
#define BROWS 256
#define BCAP 14336           // LDS edge capacity (mean 8192, +68 sigma)
#define EMAX 6400000

typedef __hip_bfloat16 bf16;
static __device__ __forceinline__ float b2f(bf16 v) { return __bfloat162float(v); }
static __device__ __forceinline__ float blo(unsigned u) { return __uint_as_float(u << 16); }
static __device__ __forceinline__ float bhi(unsigned u) { return __uint_as_float(u & 0xFFFF0000u); }

// ---------------- dtype detection (1 = fp32, 0 = bf16) ----------------
__global__ void detect_k(const unsigned int* __restrict__ xb, int* __restrict__ flag) {
    __shared__ int cs;
    int t = threadIdx.x;
    if (t == 0) cs = 0;
    __syncthreads();
    unsigned w = xb[t];
    unsigned e = (w >> 7) & 0xFFu;
    if (e >= 0x30u && e <= 0x43u) atomicAdd(&cs, 1);
    __syncthreads();
    if (t == 0) flag[0] = (cs < 128) ? 1 : 0;
}

// ---------------- CSR build ----------------

__global__ __launch_bounds__(256) void hist_k(const int* __restrict__ rows, const int* __restrict__ cols,
                                              int* __restrict__ cnt, int E) {
    int e = blockIdx.x * 256 + threadIdx.x;
    if (e >= E) return;
    int r = rows[e], c = cols[e];
    if (r != c) atomicAdd(&cnt[r], 1);
}

__global__ __launch_bounds__(256) void dinv_k(const int* __restrict__ cnt, float* __restrict__ dinv, int n) {
    int i = blockIdx.x * 256 + threadIdx.x;
    if (i >= n) return;
    int d = cnt[i];
    dinv[i] = (d > 0) ? rsqrtf((float)d) : 0.f;
}

__global__ __launch_bounds__(256) void scan_block_k(const int* __restrict__ cnt, int* __restrict__ ptr,
                                                    int* __restrict__ bsum, int n) {
    __shared__ int s[256];
    int t = threadIdx.x;
    int i = blockIdx.x * 256 + t;
    int v = (i < n) ? cnt[i] : 0;
    s[t] = v;
    __syncthreads();
    for (int off = 1; off < 256; off <<= 1) {
        int x = (t >= off) ? s[t - off] : 0;
        __syncthreads();
        s[t] += x;
        __syncthreads();
    }
    if (i < n) ptr[i] = s[t] - v;  // exclusive within block
    if (t == 255) bsum[blockIdx.x] = s[255];
}

__global__ __launch_bounds__(1024) void scan_sums_k(int* __restrict__ bsum, int nb, int* __restrict__ ptr, int n) {
    __shared__ int s[1024];
    int t = threadIdx.x;
    int v = (t < nb) ? bsum[t] : 0;
    s[t] = v;
    __syncthreads();
    for (int off = 1; off < 1024; off <<= 1) {
        int x = (t >= off) ? s[t - off] : 0;
        __syncthreads();
        s[t] += x;
        __syncthreads();
    }
    if (t < nb) bsum[t] = s[t] - v;   // exclusive block offsets
    if (t == 1023) ptr[n] = s[1023];  // total non-self edges
}

__global__ __launch_bounds__(256) void scan_add_k(int* __restrict__ ptr, const int* __restrict__ bsum, int n) {
    int i = blockIdx.x * 256 + threadIdx.x;
    if (i < n) ptr[i] += bsum[blockIdx.x];
}

// ---- two-phase binned scatter ----

__global__ __launch_bounds__(256) void tail_init_k(const int* __restrict__ ptr, int* __restrict__ tail8, int nbuk) {
    int i = blockIdx.x * 256 + threadIdx.x;
    if (i < 8 * nbuk) {
        int b = i % nbuk;
        tail8[i] = ptr[b << SB];
    }
}

__global__ __launch_bounds__(256) void binA_k(const int* __restrict__ rows, const int* __restrict__ cols,
                                              int* __restrict__ tail8, unsigned* __restrict__ colB,
                                              int nbuk, int E) {
    int e = blockIdx.x * 256 + threadIdx.x;
    if (e >= E) return;
    int r = rows[e], c = cols[e];
    if (r == c) return;
    int plane = blockIdx.x & 7;  // round-robin block->XCD heuristic; any value correct
    int b = r >> SB;
    int pos = atomicAdd(&tail8[plane * nbuk + b], 1);
    colB[(size_t)plane * EMAX + pos] = ((unsigned)(r & (BROWS - 1)) << 18) | (unsigned)c;
}

__global__ __launch_bounds__(256) void binB_k(const int* __restrict__ ptr, const int* __restrict__ tail8,
                                              const unsigned* __restrict__ colB, int nbuk,
                                              int* __restrict__ colS, int* __restrict__ gfill, int n) {
    __shared__ int lptr[BROWS + 1];
    __shared__ int lfill[BROWS];
    __shared__ int scol[BCAP];
    int b = blockIdx.x;
    int t = threadIdx.x;
    int rowbase = b << SB;
    int rowend = rowbase + BROWS;
    if (rowend > n) rowend = n;
    int nrows = rowend - rowbase;
    for (int i = t; i <= nrows; i += 256) lptr[i] = ptr[rowbase + i];
    for (int i = t; i < BROWS; i += 256) lfill[i] = 0;
    __syncthreads();
    int segStart = lptr[0];
    int count = lptr[nrows] - segStart;
    if (count <= BCAP) {
        for (int p = 0; p < 8; ++p) {
            int cntp = tail8[p * nbuk + b] - segStart;
            const unsigned* src = colB + (size_t)p * EMAX + segStart;
            for (int i = t; i < cntp; i += 256) {
                unsigned pk = src[i];
                int rl = pk >> 18;
                int c = (int)(pk & 0x3FFFFu);
                int s = atomicAdd(&lfill[rl], 1);
                scol[(lptr[rl] - segStart) + s] = c;
            }
        }
        __syncthreads();
        for (int i = t; i < count; i += 256) colS[segStart + i] = scol[i];
    } else {  // statistically unreachable fallback (correctness net)
        for (int p = 0; p < 8; ++p) {
            int cntp = tail8[p * nbuk + b] - segStart;
            const unsigned* src = colB + (size_t)p * EMAX + segStart;
            for (int i = t; i < cntp; i += 256) {
                unsigned pk = src[i];
                int rl = pk >> 18;
                int c = (int)(pk & 0x3FFFFu);
                int s = atomicAdd(&gfill[rowbase + rl], 1);
                colS[lptr[rl] + s] = c;
            }
        }
    }
}

// ---------------- feature staging ----------------

__global__ __launch_bounds__(256) void convert_x_k(const void* __restrict__ x, float* __restrict__ TxAll,
                                                   int n, const int* __restrict__ flag) {
    int isf = flag[0];
    int i = blockIdx.x * 256 + threadIdx.x;
    if (i >= n * 3) return;
    int r = i / 3, c = i - r * 3;
    float v;
    if (isf) v = ((const float*)x)[i];
    else     v = b2f(((const bf16*)x)[i]);
    TxAll[(size_t)r * 18 + c] = v;
}

// ---------------- propagation ----------------

__global__ __launch_bounds__(256) void prop_narrow_k(const int* __restrict__ ptr, const int* __restrict__ colS,
                                                     const float* __restrict__ dinv, const float* __restrict__ hin,
                                                     const float* __restrict__ sub, float* __restrict__ o,
                                                     int ld, int n, float alpha, int useSub) {
    int wv = threadIdx.x >> 6, lane = threadIdx.x & 63;
    int r = blockIdx.x * 4 + wv;
    if (r >= n) return;
    int s = ptr[r], e = ptr[r + 1];
    float dr = dinv[r];
    float a0 = 0.f, a1 = 0.f, a2 = 0.f;
    for (int idx = s + lane; idx < e; idx += 64) {
        int c = colS[idx];
        float nrm = -dr * dinv[c];
        const float* hp = hin + (size_t)c * ld;
        a0 += nrm * hp[0];
        a1 += nrm * hp[1];
        a2 += nrm * hp[2];
    }
    for (int off2 = 32; off2 > 0; off2 >>= 1) {
        a0 += __shfl_down(a0, off2);
        a1 += __shfl_down(a1, off2);
        a2 += __shfl_down(a2, off2);
    }
    if (lane == 0) {
        size_t b = (size_t)r * ld;
        float v0 = alpha * a0, v1 = alpha * a1, v2 = alpha * a2;
        if (useSub) { v0 -= sub[b + 0]; v1 -= sub[b + 1]; v2 -= sub[b + 2]; }
        o[b + 0] = v0; o[b + 1] = v1; o[b + 2] = v2;
    }
}

// cin == 64*VEC: wave per row, lane = channel; edges shfl-broadcast; x4 unroll.
template <int VEC>
__global__ __launch_bounds__(256) void prop_wide_k(const int* __restrict__ ptr, const int* __restrict__ colS,
                                                   const float* __restrict__ dinv, const float* __restrict__ hin,
                                                   const float* __restrict__ sub, float* __restrict__ o,
                                                   int ld, int n, float alpha, int useSub) {
    int wv = threadIdx.x >> 6, lane = threadIdx.x & 63;
    int r = blockIdx.x * 4 + wv;
    if (r >= n) return;
    int s = ptr[r], e = ptr[r + 1];
    float dr = dinv[r];
    float acc[VEC];
#pragma unroll
    for (int v = 0; v < VEC; ++v) acc[v] = 0.f;
    for (int base = s; base < e; base += 64) {
        int idx = base + lane;
        int c = 0;
        float dc = 0.f;
        if (idx < e) { c = colS[idx]; dc = dinv[c]; }
        int cnt2 = e - base;
        if (cnt2 > 64) cnt2 = 64;
        int j = 0;
        for (; j + 4 <= cnt2; j += 4) {
            int cc0 = __shfl(c, j), cc1 = __shfl(c, j + 1), cc2 = __shfl(c, j + 2), cc3 = __shfl(c, j + 3);
            float n0 = -dr * __shfl(dc, j), n1 = -dr * __shfl(dc, j + 1);
            float n2 = -dr * __shfl(dc, j + 2), n3 = -dr * __shfl(dc, j + 3);
            const float* h0 = hin + (size_t)cc0 * ld + lane;
            const float* h1 = hin + (size_t)cc1 * ld + lane;
            const float* h2 = hin + (size_t)cc2 * ld + lane;
            const float* h3 = hin + (size_t)cc3 * ld + lane;
            float v0[VEC], v1[VEC], v2[VEC], v3[VEC];
#pragma unroll
            for (int v = 0; v < VEC; ++v) { v0[v] = h0[v * 64]; v1[v] = h1[v * 64]; v2[v] = h2[v * 64]; v3[v] = h3[v * 64]; }
#pragma unroll
            for (int v = 0; v < VEC; ++v) acc[v] += n0 * v0[v] + n1 * v1[v] + n2 * v2[v] + n3 * v3[v];
        }
        for (; j < cnt2; ++j) {
            int cc = __shfl(c, j);
            float nrm = -dr * __shfl(dc, j);
            const float* hp = hin + (size_t)cc * ld + lane;
#pragma unroll
            for (int v = 0; v < VEC; ++v) acc[v] += nrm * hp[v * 64];
        }
    }
    size_t rb = (size_t)r * ld + lane;
#pragma unroll
    for (int v = 0; v < VEC; ++v) {
        float val = alpha * acc[v];
        if (useSub) val -= sub[rb + v * 64];
        o[rb + v * 64] = val;
    }
}

// ---------------- GEMM: C = [C +] (A @ W[koff..]) [+ bias] [relu] ----------------
// flags: 1 = relu, 2 = accumulate into C, 4 = add bias. koff = W element offset.

__global__ __launch_bounds__(256) void gemm_k(const float* __restrict__ A, int lda,
                                              const void* __restrict__ W, size_t koff,
                                              const void* __restrict__ bias,
                                              float* __restrict__ C, int M, int N, int K, int flags,
                                              const int* __restrict__ flag) {
    __shared__ float As[16][65];
    __shared__ float Ws[16][64];
    int isf = flag[0];
    int t = threadIdx.x;
    int tn = t & 15, tm = t >> 4;
    int m0 = blockIdx.y * 64, n0 = blockIdx.x * 64;
    float acc[4][4] = {};
    for (int k0 = 0; k0 < K; k0 += 16) {
#pragma unroll
        for (int i = 0; i < 4; ++i) {
            int idx = i * 256 + t;
            int m = idx >> 4, k = idx & 15;
            int gm = m0 + m, gk = k0 + k;
            As[k][m] = (gm < M && gk < K) ? A[(size_t)gm * lda + gk] : 0.f;
        }
        if (isf) {
            const float* Wf = (const float*)W + koff;
#pragma unroll
            for (int i = 0; i < 4; ++i) {
                int idx = i * 256 + t;
                int k = idx >> 6, nn = idx & 63;
                int gk = k0 + k;
                Ws[k][nn] = (gk < K) ? Wf[(size_t)gk * N + n0 + nn] : 0.f;
            }
        } else {
            const bf16* Wh = (const bf16*)W + koff;
#pragma unroll
            for (int i = 0; i < 4; ++i) {
                int idx = i * 256 + t;
                int k = idx >> 6, nn = idx & 63;
                int gk = k0 + k;
                Ws[k][nn] = (gk < K) ? b2f(Wh[(size_t)gk * N + n0 + nn]) : 0.f;
            }
        }
        __syncthreads();
#pragma unroll
        for (int kk = 0; kk < 16; ++kk) {
            float a[4], b[4];
#pragma unroll
            for (int i = 0; i < 4; ++i) a[i] = As[kk][tm * 4 + i];
#pragma unroll
            for (int j = 0; j < 4; ++j) b[j] = Ws[kk][tn * 4 + j];
#pragma unroll
            for (int i = 0; i < 4; ++i)
#pragma unroll
                for (int j = 0; j < 4; ++j) acc[i][j] += a[i] * b[j];
        }
        __syncthreads();
    }
#pragma unroll
    for (int i = 0; i < 4; ++i) {
        int gm = m0 + tm * 4 + i;
        if (gm >= M) continue;
#pragma unroll
        for (int j = 0; j < 4; ++j) {
            int gn = n0 + tn * 4 + j;
            size_t ci = (size_t)gm * N + gn;
            float v = acc[i][j];
            if (flags & 4) {
                if (isf) v += ((const float*)bias)[gn];
                else     v += b2f(((const bf16*)bias)[gn]);
            }
            if (flags & 2) v += C[ci];
            if (flags & 1) v = fmaxf(v, 0.f);
            C[ci] = v;
        }
    }
}

// ---------------- pooling ----------------

__global__ __launch_bounds__(256) void pool_k(const float* __restrict__ in, const int* __restrict__ pcols,
                                              float* __restrict__ out, int n_out, int C, int ld) {
    int idx = blockIdx.x * 256 + threadIdx.x;
    if (idx >= n_out * C) return;
    int r = idx / C, ch = idx - r * C;
    const int* pc = pcols + (size_t)r * 4;
    float ssum = 0.f;
#pragma unroll
    for (int f = 0; f < 4; ++f) ssum += in[(size_t)pc[f] * C + ch];
    out[(size_t)r * ld + ch] = 0.25f * ssum;
}

// ---------------- final linear ----------------

__global__ __launch_bounds__(256) void linear10_k(const float* __restrict__ h, const void* __restrict__ lw,
                                                  float* __restrict__ accum, int LIN, const int* __restrict__ flag) {
    int isf = flag[0];
    int c = blockIdx.y;
    int t = threadIdx.x;
    int nvec = LIN >> 3;
    int stride = gridDim.x * 256;
    float p = 0.f;
    const float4* h4 = (const float4*)h;
    if (isf) {
        const float4* lw4 = (const float4*)lw + (size_t)c * (LIN >> 2);
        for (int i = blockIdx.x * 256 + t; i < nvec; i += stride) {
            float4 a0 = h4[2 * i], a1 = h4[2 * i + 1];
            float4 b0 = lw4[2 * i], b1 = lw4[2 * i + 1];
            p += a0.x * b0.x + a0.y * b0.y + a0.z * b0.z + a0.w * b0.w
               + a1.x * b1.x + a1.y * b1.y + a1.z * b1.z + a1.w * b1.w;
        }
    } else {
        const uint4* lwv = (const uint4*)lw + (size_t)c * nvec;
        for (int i = blockIdx.x * 256 + t; i < nvec; i += stride) {
            uint4 w4 = lwv[i];
            float4 a0 = h4[2 * i], a1 = h4[2 * i + 1];
            p += a0.x * blo(w4.x) + a0.y * bhi(w4.x)
               + a0.z * blo(w4.y) + a0.w * bhi(w4.y)
               + a1.x * blo(w4.z) + a1.y * bhi(w4.z)
               + a1.z * blo(w4.w) + a1.w * bhi(w4.w);
        }
    }
    for (int off2 = 32; off2 > 0; off2 >>= 1) p += __shfl_down(p, off2);
    __shared__ float wsum[4];
    int wv = t >> 6, lane = t & 63;
    if (lane == 0) wsum[wv] = p;
    __syncthreads();
    if (t == 0) unsafeAtomicAdd(&accum[c], wsum[0] + wsum[1] + wsum[2] + wsum[3]);
}

__global__ void finalize_k(const float* __restrict__ accum, const void* __restrict__ lb,
                           void* __restrict__ outp, const int* __restrict__ flag) {
    int isf = flag[0];
    int t = threadIdx.x;
    if (t < NCLS) {
        float lbv;
        if (isf) lbv = ((const float*)lb)[t];
        else     lbv = b2f(((const bf16*)lb)[t]);
        float v = accum[t] + lbv;
        if (isf) ((float*)outp)[t] = v;
        else     ((bf16*)outp)[t] = __float2bfloat16(v);
    }
}

__global__ void diag_k(void* __restrict__ outp, float val, const int* __restrict__ flag) {
    int isf = flag[0];
    int t = threadIdx.x;
    if (t < NCLS) {
        if (isf) ((float*)outp)[t] = val;
        else     ((bf16*)outp)[t] = __float2bfloat16(val);
    }
}

// ---------------- orchestration ----------------

extern "C" void kernel_launch(void* const* d_in, const int* in_sizes, int n_in,
                              void* d_out, int out_size, void* d_ws, size_t ws_size,
                              hipStream_t stream) {
    const void* x  = d_in[0];
    const int* ei0 = (const int*)d_in[1];
    const int* ei1 = (const int*)d_in[2];
    const int* ei2 = (const int*)d_in[3];
    const int* pc0 = (const int*)d_in[4];
    const int* pc1 = (const int*)d_in[5];
    const void* w0 = d_in[6];
    const void* b0 = d_in[7];
    const void* w1 = d_in[8];
    const void* b1 = d_in[9];
    const void* w2 = d_in[10];
    const void* b2 = d_in[11];
    const void* lw = d_in[12];
    const void* lb = d_in[13];

    const int E0 = in_sizes[1] / 2, E1 = in_sizes[2] / 2, E2 = in_sizes[3] / 2;

    // ---- workspace layout (~361 MB; ws is ~512 MB per harness poison) ----
    char* base = (char*)d_ws;
    size_t off = 0;
    auto alloc = [&](size_t bytes) -> void* {
        void* p = base + off;
        off += (bytes + 255) & ~(size_t)255;
        return p;
    };
    float*    TxAll = (float*)alloc((size_t)19200000 * 4);   // max(N0*18, N1*384, N2*768)
    float*    OutB  = (float*)alloc((size_t)12800000 * 4);   // max(N0*64, N1*128, N2*256)
    int*      colS  = (int*)alloc((size_t)EMAX * 4);
    unsigned* colB  = (unsigned*)alloc((size_t)8 * EMAX * 4);  // 8 planes
    int*      ptr   = (int*)alloc((size_t)(N0 + 1) * 4);
    int*      cnt   = (int*)alloc((size_t)N0 * 4);           // reused as fallback fill
    float*    dinv  = (float*)alloc((size_t)N0 * 4);
    int*      bsum  = (int*)alloc(4096);
    float*    accum = (float*)alloc(64);                     // floats 0..9; int at +64B = dtype flag
    int*      flag  = (int*)(accum + 16);
    int*      tail8 = (int*)alloc((size_t)8 * 1024 * 4);

    detect_k<<<1, 256, 0, stream>>>((const unsigned int*)x, flag);

    const size_t NEED = 361000000;
    if (ws_size < NEED) {
        diag_k<<<1, 64, 0, stream>>>(d_out, (float)(ws_size >> 20), flag);
        return;
    }

    struct Lvl {
        int n, E, cin, cout;
        const int *rows, *cols;
        const void *w, *b;
        int relu;
    };
    Lvl L[3] = {
        {N0, E0, 3, 64, ei0, ei0 + E0, w0, b0, 1},
        {N1, E1, 64, 128, ei1, ei1 + E1, w1, b1, 1},
        {N2, E2, 128, 256, ei2, ei2 + E2, w2, b2, 0},
    };

    convert_x_k<<<(N0 * 3 + 255) / 256, 256, 0, stream>>>(x, TxAll, N0, flag);

    for (int li = 0; li < 3; ++li) {
        const Lvl& v = L[li];
        int n = v.n, E = v.E, cin = v.cin, cout = v.cout;
        int nb = (n + 255) / 256;
        int pgrid = (n + 3) / 4;
        int ld = KCH * cin;
        int nbuk = (n + BROWS - 1) >> SB;

        // CSR build (self-loops excluded => row length == deg)
        hipMemsetAsync(cnt, 0, (size_t)n * 4, stream);
        hist_k<<<(E + 255) / 256, 256, 0, stream>>>(v.rows, v.cols, cnt, E);
        dinv_k<<<nb, 256, 0, stream>>>(cnt, dinv, n);
        scan_block_k<<<nb, 256, 0, stream>>>(cnt, ptr, bsum, n);
        scan_sums_k<<<1, 1024, 0, stream>>>(bsum, nb, ptr, n);
        scan_add_k<<<nb, 256, 0, stream>>>(ptr, bsum, n);
        // two-phase binned scatter
        tail_init_k<<<(8 * nbuk + 255) / 256, 256, 0, stream>>>(ptr, tail8, nbuk);
        binA_k<<<(E + 255) / 256, 256, 0, stream>>>(v.rows, v.cols, tail8, colB, nbuk, E);
        hipMemsetAsync(cnt, 0, (size_t)n * 4, stream);  // fallback fill (statistically unused)
        binB_k<<<nbuk, 256, 0, stream>>>(ptr, tail8, colB, nbuk, colS, cnt, n);

        // Chebyshev recurrence into fused slots (slot k at column k*cin, row stride ld)
        for (int k = 1; k < KCH; ++k) {
            const float* hin = TxAll + (size_t)(k - 1) * cin;
            const float* sub = (k >= 2) ? (TxAll + (size_t)(k - 2) * cin) : nullptr;
            float* o = TxAll + (size_t)k * cin;
            float alpha = (k >= 2) ? 2.f : 1.f;
            if (cin == 3)
                prop_narrow_k<<<pgrid, 256, 0, stream>>>(ptr, colS, dinv, hin, sub, o, ld, n, alpha, k >= 2);
            else if (cin == 64)
                prop_wide_k<1><<<pgrid, 256, 0, stream>>>(ptr, colS, dinv, hin, sub, o, ld, n, alpha, k >= 2);
            else
                prop_wide_k<2><<<pgrid, 256, 0, stream>>>(ptr, colS, dinv, hin, sub, o, ld, n, alpha, k >= 2);
        }

        // fused 6-slot GEMM: OutB[n,cout] = TxAll[n,ld] @ w[ld,cout] + bias (+relu)
        dim3 gg(cout / 64, (n + 63) / 64);
        gemm_k<<<gg, 256, 0, stream>>>(TxAll, ld, v.w, 0, v.b, OutB, n, cout, ld, 4 | (v.relu ? 1 : 0), flag);

        // pool into next level's slot0
        if (li == 0)
            pool_k<<<(N1 * 64 + 255) / 256, 256, 0, stream>>>(OutB, pc0, TxAll, N1, 64, KCH * 64);
        else if (li == 1)
            pool_k<<<(N2 * 128 + 255) / 256, 256, 0, stream>>>(OutB, pc1, TxAll, N2, 128, KCH * 128);
    }

    hipMemsetAsync(accum, 0, 64, stream);
    {
        dim3 lg(128, NCLS);
        linear10_k<<<lg, 256, 0, stream>>>(OutB, lw, accum, N2 * 256, flag);
    }
    finalize_k<<<1, 64, 0, stream>>>(accum, lb, d_out, flag);
}

// Round 6
// 2187.666 us; speedup vs baseline: 1.2231x; 1.2231x over previous
//
#include <hip/hip_runtime.h>
#include <hip/hip_bf16.h>

// ChebNet classifier: 3x ChebConv(K=6) + pool + linear. fp32 internal.
// Round 6: binA rewritten with per-block LDS bucket staging — appends go to
// LDS; only full 64B (16-entry) chunks are flushed to the global bucket tail,
// so no sub-line global writes -> write amplification <=2x (round 5 measured
// 7x: planes shared tail lines across non-coherent XCD L2s, each writing back
// partial copies). Single colB plane; binB drops the plane loop.

#define N0 200000
#define N1 50000
#define N2 12500
#define KCH 6
#define NCLS 10

#define SB 8                 // bucket = 256 rows
#define BROWS 256
#define BCAP 14336           // binB LDS edge capacity (mean 8192, +68 sigma)
#define EMAX 6400000
#define QCAP 19              // binA per-bucket LDS staging entries
#define NBUK_MAX 800

typedef __hip_bfloat16 bf16;
static __device__ __forceinline__ float b2f(bf16 v) { return __bfloat162float(v); }
static __device__ __forceinline__ float blo(unsigned u) { return __uint_as_float(u << 16); }
static __device__ __forceinline__ float bhi(unsigned u) { return __uint_as_float(u & 0xFFFF0000u); }

// ---------------- dtype detection (1 = fp32, 0 = bf16) ----------------
__global__ void detect_k(const unsigned int* __restrict__ xb, int* __restrict__ flag) {
    __shared__ int cs;
    int t = threadIdx.x;
    if (t == 0) cs = 0;
    __syncthreads();
    unsigned w = xb[t];
    unsigned e = (w >> 7) & 0xFFu;
    if (e >= 0x30u && e <= 0x43u) atomicAdd(&cs, 1);
    __syncthreads();
    if (t == 0) flag[0] = (cs < 128) ? 1 : 0;
}

// ---------------- CSR build ----------------

__global__ __launch_bounds__(256) void hist_k(const int* __restrict__ rows, const int* __restrict__ cols,
                                              int* __restrict__ cnt, int E) {
    int e = blockIdx.x * 256 + threadIdx.x;
    if (e >= E) return;
    int r = rows[e], c = cols[e];
    if (r != c) atomicAdd(&cnt[r], 1);
}

__global__ __launch_bounds__(256) void dinv_k(const int* __restrict__ cnt, float* __restrict__ dinv, int n) {
    int i = blockIdx.x * 256 + threadIdx.x;
    if (i >= n) return;
    int d = cnt[i];
    dinv[i] = (d > 0) ? rsqrtf((float)d) : 0.f;
}

__global__ __launch_bounds__(256) void scan_block_k(const int* __restrict__ cnt, int* __restrict__ ptr,
                                                    int* __restrict__ bsum, int n) {
    __shared__ int s[256];
    int t = threadIdx.x;
    int i = blockIdx.x * 256 + t;
    int v = (i < n) ? cnt[i] : 0;
    s[t] = v;
    __syncthreads();
    for (int off = 1; off < 256; off <<= 1) {
        int x = (t >= off) ? s[t - off] : 0;
        __syncthreads();
        s[t] += x;
        __syncthreads();
    }
    if (i < n) ptr[i] = s[t] - v;  // exclusive within block
    if (t == 255) bsum[blockIdx.x] = s[255];
}

__global__ __launch_bounds__(1024) void scan_sums_k(int* __restrict__ bsum, int nb, int* __restrict__ ptr, int n) {
    __shared__ int s[1024];
    int t = threadIdx.x;
    int v = (t < nb) ? bsum[t] : 0;
    s[t] = v;
    __syncthreads();
    for (int off = 1; off < 1024; off <<= 1) {
        int x = (t >= off) ? s[t - off] : 0;
        __syncthreads();
        s[t] += x;
        __syncthreads();
    }
    if (t < nb) bsum[t] = s[t] - v;   // exclusive block offsets
    if (t == 1023) ptr[n] = s[1023];  // total non-self edges
}

__global__ __launch_bounds__(256) void scan_add_k(int* __restrict__ ptr, const int* __restrict__ bsum, int n) {
    int i = blockIdx.x * 256 + threadIdx.x;
    if (i < n) ptr[i] += bsum[blockIdx.x];
}

// ---- two-phase binned scatter, LDS line-staged ----

__global__ __launch_bounds__(256) void tail_init_k(const int* __restrict__ ptr, int* __restrict__ tail, int nbuk) {
    int i = blockIdx.x * 256 + threadIdx.x;
    if (i < nbuk) tail[i] = ptr[i << SB];
}

// dynamic LDS: scnt[nbuk] then stage[nbuk*QCAP]
__global__ __launch_bounds__(256) void binA_k(const int* __restrict__ rows, const int* __restrict__ cols,
                                              int* __restrict__ tail, unsigned* __restrict__ colB,
                                              int nbuk, int E) {
    extern __shared__ int sh[];
    int* scnt = sh;
    int* stage = sh + nbuk;
    int t = threadIdx.x;
    for (int i = t; i < nbuk; i += 256) scnt[i] = 0;
    __syncthreads();
    int tile = (E + gridDim.x - 1) / gridDim.x;
    int beg = blockIdx.x * tile;
    int end = beg + tile;
    if (end > E) end = E;
    for (int base = beg; base < end; base += 256) {
        int idx = base + t;
        int valid = 0, b = 0;
        unsigned pk = 0;
        if (idx < end) {
            int r = rows[idx], c = cols[idx];
            if (r != c) {
                valid = 1;
                b = r >> SB;
                pk = ((unsigned)(r & (BROWS - 1)) << 18) | (unsigned)c;
            }
        }
        if (valid) {
            int slot = atomicAdd(&scnt[b], 1);
            if (slot < QCAP) stage[b * QCAP + slot] = (int)pk;
            else {  // rare spill: single-entry global append (correct, slow)
                int pos = atomicAdd(&tail[b], 1);
                colB[pos] = pk;
            }
        }
        __syncthreads();
        // flush full 16-entry (64B) chunks
        for (int bb = t; bb < nbuk; bb += 256) {
            int cnt2 = scnt[bb];
            if (cnt2 > QCAP) cnt2 = QCAP;
            int nf = cnt2 & ~15;
            if (nf > 0) {
                int pos = atomicAdd(&tail[bb], nf);
                for (int i = 0; i < nf; ++i) colB[pos + i] = (unsigned)stage[bb * QCAP + i];
                for (int i = 0; i < cnt2 - nf; ++i) stage[bb * QCAP + i] = stage[bb * QCAP + nf + i];
            }
            scnt[bb] = cnt2 - nf;
        }
        __syncthreads();
    }
    // final flush (partial chunks)
    for (int bb = t; bb < nbuk; bb += 256) {
        int cnt2 = scnt[bb];
        if (cnt2 > 0) {
            int pos = atomicAdd(&tail[bb], cnt2);
            for (int i = 0; i < cnt2; ++i) colB[pos + i] = (unsigned)stage[bb * QCAP + i];
        }
    }
}

__global__ __launch_bounds__(256) void binB_k(const int* __restrict__ ptr,
                                              const unsigned* __restrict__ colB,
                                              int* __restrict__ colS, int* __restrict__ gfill, int n) {
    __shared__ int lptr[BROWS + 1];
    __shared__ int lfill[BROWS];
    __shared__ int scol[BCAP];
    int b = blockIdx.x;
    int t = threadIdx.x;
    int rowbase = b << SB;
    int rowend = rowbase + BROWS;
    if (rowend > n) rowend = n;
    int nrows = rowend - rowbase;
    for (int i = t; i <= nrows; i += 256) lptr[i] = ptr[rowbase + i];
    for (int i = t; i < BROWS; i += 256) lfill[i] = 0;
    __syncthreads();
    int segStart = lptr[0];
    int count = lptr[nrows] - segStart;
    if (count <= BCAP) {
        const unsigned* src = colB + segStart;
        for (int i = t; i < count; i += 256) {
            unsigned pk = src[i];
            int rl = pk >> 18;
            int c = (int)(pk & 0x3FFFFu);
            int s = atomicAdd(&lfill[rl], 1);
            scol[(lptr[rl] - segStart) + s] = c;
        }
        __syncthreads();
        for (int i = t; i < count; i += 256) colS[segStart + i] = scol[i];
    } else {  // statistically unreachable fallback (correctness net)
        const unsigned* src = colB + segStart;
        for (int i = t; i < count; i += 256) {
            unsigned pk = src[i];
            int rl = pk >> 18;
            int c = (int)(pk & 0x3FFFFu);
            int s = atomicAdd(&gfill[rowbase + rl], 1);
            colS[lptr[rl] + s] = c;
        }
    }
}

// ---------------- feature staging ----------------

__global__ __launch_bounds__(256) void convert_x_k(const void* __restrict__ x, float* __restrict__ TxAll,
                                                   int n, const int* __restrict__ flag) {
    int isf = flag[0];
    int i = blockIdx.x * 256 + threadIdx.x;
    if (i >= n * 3) return;
    int r = i / 3, c = i - r * 3;
    float v;
    if (isf) v = ((const float*)x)[i];
    else     v = b2f(((const bf16*)x)[i]);
    TxAll[(size_t)r * 18 + c] = v;
}

// ---------------- propagation ----------------

__global__ __launch_bounds__(256) void prop_narrow_k(const int* __restrict__ ptr, const int* __restrict__ colS,
                                                     const float* __restrict__ dinv, const float* __restrict__ hin,
                                                     const float* __restrict__ sub, float* __restrict__ o,
                                                     int ld, int n, float alpha, int useSub) {
    int wv = threadIdx.x >> 6, lane = threadIdx.x & 63;
    int r = blockIdx.x * 4 + wv;
    if (r >= n) return;
    int s = ptr[r], e = ptr[r + 1];
    float dr = dinv[r];
    float a0 = 0.f, a1 = 0.f, a2 = 0.f;
    for (int idx = s + lane; idx < e; idx += 64) {
        int c = colS[idx];
        float nrm = -dr * dinv[c];
        const float* hp = hin + (size_t)c * ld;
        a0 += nrm * hp[0];
        a1 += nrm * hp[1];
        a2 += nrm * hp[2];
    }
    for (int off2 = 32; off2 > 0; off2 >>= 1) {
        a0 += __shfl_down(a0, off2);
        a1 += __shfl_down(a1, off2);
        a2 += __shfl_down(a2, off2);
    }
    if (lane == 0) {
        size_t b = (size_t)r * ld;
        float v0 = alpha * a0, v1 = alpha * a1, v2 = alpha * a2;
        if (useSub) { v0 -= sub[b + 0]; v1 -= sub[b + 1]; v2 -= sub[b + 2]; }
        o[b + 0] = v0; o[b + 1] = v1; o[b + 2] = v2;
    }
}

// cin == 64*VEC: wave per row, lane = channel; edges shfl-broadcast; x4 unroll.
template <int VEC>
__global__ __launch_bounds__(256) void prop_wide_k(const int* __restrict__ ptr, const int* __restrict__ colS,
                                                   const float* __restrict__ dinv, const float* __restrict__ hin,
                                                   const float* __restrict__ sub, float* __restrict__ o,
                                                   int ld, int n, float alpha, int useSub) {
    int wv = threadIdx.x >> 6, lane = threadIdx.x & 63;
    int r = blockIdx.x * 4 + wv;
    if (r >= n) return;
    int s = ptr[r], e = ptr[r + 1];
    float dr = dinv[r];
    float acc[VEC];
#pragma unroll
    for (int v = 0; v < VEC; ++v) acc[v] = 0.f;
    for (int base = s; base < e; base += 64) {
        int idx = base + lane;
        int c = 0;
        float dc = 0.f;
        if (idx < e) { c = colS[idx]; dc = dinv[c]; }
        int cnt2 = e - base;
        if (cnt2 > 64) cnt2 = 64;
        int j = 0;
        for (; j + 4 <= cnt2; j += 4) {
            int cc0 = __shfl(c, j), cc1 = __shfl(c, j + 1), cc2 = __shfl(c, j + 2), cc3 = __shfl(c, j + 3);
            float n0 = -dr * __shfl(dc, j), n1 = -dr * __shfl(dc, j + 1);
            float n2 = -dr * __shfl(dc, j + 2), n3 = -dr * __shfl(dc, j + 3);
            const float* h0 = hin + (size_t)cc0 * ld + lane;
            const float* h1 = hin + (size_t)cc1 * ld + lane;
            const float* h2 = hin + (size_t)cc2 * ld + lane;
            const float* h3 = hin + (size_t)cc3 * ld + lane;
            float v0[VEC], v1[VEC], v2[VEC], v3[VEC];
#pragma unroll
            for (int v = 0; v < VEC; ++v) { v0[v] = h0[v * 64]; v1[v] = h1[v * 64]; v2[v] = h2[v * 64]; v3[v] = h3[v * 64]; }
#pragma unroll
            for (int v = 0; v < VEC; ++v) acc[v] += n0 * v0[v] + n1 * v1[v] + n2 * v2[v] + n3 * v3[v];
        }
        for (; j < cnt2; ++j) {
            int cc = __shfl(c, j);
            float nrm = -dr * __shfl(dc, j);
            const float* hp = hin + (size_t)cc * ld + lane;
#pragma unroll
            for (int v = 0; v < VEC; ++v) acc[v] += nrm * hp[v * 64];
        }
    }
    size_t rb = (size_t)r * ld + lane;
#pragma unroll
    for (int v = 0; v < VEC; ++v) {
        float val = alpha * acc[v];
        if (useSub) val -= sub[rb + v * 64];
        o[rb + v * 64] = val;
    }
}

// ---------------- GEMM: C = [C +] (A @ W[koff..]) [+ bias] [relu] ----------------
// flags: 1 = relu, 2 = accumulate into C, 4 = add bias. koff = W element offset.

__global__ __launch_bounds__(256) void gemm_k(const float* __restrict__ A, int lda,
                                              const void* __restrict__ W, size_t koff,
                                              const void* __restrict__ bias,
                                              float* __restrict__ C, int M, int N, int K, int flags,
                                              const int* __restrict__ flag) {
    __shared__ float As[16][65];
    __shared__ float Ws[16][64];
    int isf = flag[0];
    int t = threadIdx.x;
    int tn = t & 15, tm = t >> 4;
    int m0 = blockIdx.y * 64, n0 = blockIdx.x * 64;
    float acc[4][4] = {};
    for (int k0 = 0; k0 < K; k0 += 16) {
#pragma unroll
        for (int i = 0; i < 4; ++i) {
            int idx = i * 256 + t;
            int m = idx >> 4, k = idx & 15;
            int gm = m0 + m, gk = k0 + k;
            As[k][m] = (gm < M && gk < K) ? A[(size_t)gm * lda + gk] : 0.f;
        }
        if (isf) {
            const float* Wf = (const float*)W + koff;
#pragma unroll
            for (int i = 0; i < 4; ++i) {
                int idx = i * 256 + t;
                int k = idx >> 6, nn = idx & 63;
                int gk = k0 + k;
                Ws[k][nn] = (gk < K) ? Wf[(size_t)gk * N + n0 + nn] : 0.f;
            }
        } else {
            const bf16* Wh = (const bf16*)W + koff;
#pragma unroll
            for (int i = 0; i < 4; ++i) {
                int idx = i * 256 + t;
                int k = idx >> 6, nn = idx & 63;
                int gk = k0 + k;
                Ws[k][nn] = (gk < K) ? b2f(Wh[(size_t)gk * N + n0 + nn]) : 0.f;
            }
        }
        __syncthreads();
#pragma unroll
        for (int kk = 0; kk < 16; ++kk) {
            float a[4], b[4];
#pragma unroll
            for (int i = 0; i < 4; ++i) a[i] = As[kk][tm * 4 + i];
#pragma unroll
            for (int j = 0; j < 4; ++j) b[j] = Ws[kk][tn * 4 + j];
#pragma unroll
            for (int i = 0; i < 4; ++i)
#pragma unroll
                for (int j = 0; j < 4; ++j) acc[i][j] += a[i] * b[j];
        }
        __syncthreads();
    }
#pragma unroll
    for (int i = 0; i < 4; ++i) {
        int gm = m0 + tm * 4 + i;
        if (gm >= M) continue;
#pragma unroll
        for (int j = 0; j < 4; ++j) {
            int gn = n0 + tn * 4 + j;
            size_t ci = (size_t)gm * N + gn;
            float v = acc[i][j];
            if (flags & 4) {
                if (isf) v += ((const float*)bias)[gn];
                else     v += b2f(((const bf16*)bias)[gn]);
            }
            if (flags & 2) v += C[ci];
            if (flags & 1) v = fmaxf(v, 0.f);
            C[ci] = v;
        }
    }
}

// ---------------- pooling ----------------

__global__ __launch_bounds__(256) void pool_k(const float* __restrict__ in, const int* __restrict__ pcols,
                                              float* __restrict__ out, int n_out, int C, int ld) {
    int idx = blockIdx.x * 256 + threadIdx.x;
    if (idx >= n_out * C) return;
    int r = idx / C, ch = idx - r * C;
    const int* pc = pcols + (size_t)r * 4;
    float ssum = 0.f;
#pragma unroll
    for (int f = 0; f < 4; ++f) ssum += in[(size_t)pc[f] * C + ch];
    out[(size_t)r * ld + ch] = 0.25f * ssum;
}

// ---------------- final linear ----------------

__global__ __launch_bounds__(256) void linear10_k(const float* __restrict__ h, const void* __restrict__ lw,
                                                  float* __restrict__ accum, int LIN, const int* __restrict__ flag) {
    int isf = flag[0];
    int c = blockIdx.y;
    int t = threadIdx.x;
    int nvec = LIN >> 3;
    int stride = gridDim.x * 256;
    float p = 0.f;
    const float4* h4 = (const float4*)h;
    if (isf) {
        const float4* lw4 = (const float4*)lw + (size_t)c * (LIN >> 2);
        for (int i = blockIdx.x * 256 + t; i < nvec; i += stride) {
            float4 a0 = h4[2 * i], a1 = h4[2 * i + 1];
            float4 b0 = lw4[2 * i], b1 = lw4[2 * i + 1];
            p += a0.x * b0.x + a0.y * b0.y + a0.z * b0.z + a0.w * b0.w
               + a1.x * b1.x + a1.y * b1.y + a1.z * b1.z + a1.w * b1.w;
        }
    } else {
        const uint4* lwv = (const uint4*)lw + (size_t)c * nvec;
        for (int i = blockIdx.x * 256 + t; i < nvec; i += stride) {
            uint4 w4 = lwv[i];
            float4 a0 = h4[2 * i], a1 = h4[2 * i + 1];
            p += a0.x * blo(w4.x) + a0.y * bhi(w4.x)
               + a0.z * blo(w4.y) + a0.w * bhi(w4.y)
               + a1.x * blo(w4.z) + a1.y * bhi(w4.z)
               + a1.z * blo(w4.w) + a1.w * bhi(w4.w);
        }
    }
    for (int off2 = 32; off2 > 0; off2 >>= 1) p += __shfl_down(p, off2);
    __shared__ float wsum[4];
    int wv = t >> 6, lane = t & 63;
    if (lane == 0) wsum[wv] = p;
    __syncthreads();
    if (t == 0) unsafeAtomicAdd(&accum[c], wsum[0] + wsum[1] + wsum[2] + wsum[3]);
}

__global__ void finalize_k(const float* __restrict__ accum, const void* __restrict__ lb,
                           void* __restrict__ outp, const int* __restrict__ flag) {
    int isf = flag[0];
    int t = threadIdx.x;
    if (t < NCLS) {
        float lbv;
        if (isf) lbv = ((const float*)lb)[t];
        else     lbv = b2f(((const bf16*)lb)[t]);
        float v = accum[t] + lbv;
        if (isf) ((float*)outp)[t] = v;
        else     ((bf16*)outp)[t] = __float2bfloat16(v);
    }
}

__global__ void diag_k(void* __restrict__ outp, float val, const int* __restrict__ flag) {
    int isf = flag[0];
    int t = threadIdx.x;
    if (t < NCLS) {
        if (isf) ((float*)outp)[t] = val;
        else     ((bf16*)outp)[t] = __float2bfloat16(val);
    }
}

// ---------------- orchestration ----------------

extern "C" void kernel_launch(void* const* d_in, const int* in_sizes, int n_in,
                              void* d_out, int out_size, void* d_ws, size_t ws_size,
                              hipStream_t stream) {
    const void* x  = d_in[0];
    const int* ei0 = (const int*)d_in[1];
    const int* ei1 = (const int*)d_in[2];
    const int* ei2 = (const int*)d_in[3];
    const int* pc0 = (const int*)d_in[4];
    const int* pc1 = (const int*)d_in[5];
    const void* w0 = d_in[6];
    const void* b0 = d_in[7];
    const void* w1 = d_in[8];
    const void* b1 = d_in[9];
    const void* w2 = d_in[10];
    const void* b2 = d_in[11];
    const void* lw = d_in[12];
    const void* lb = d_in[13];

    const int E0 = in_sizes[1] / 2, E1 = in_sizes[2] / 2, E2 = in_sizes[3] / 2;

    // ---- workspace layout (~182 MB; ws is ~512 MB per harness poison) ----
    char* base = (char*)d_ws;
    size_t off = 0;
    auto alloc = [&](size_t bytes) -> void* {
        void* p = base + off;
        off += (bytes + 255) & ~(size_t)255;
        return p;
    };
    float*    TxAll = (float*)alloc((size_t)19200000 * 4);   // max(N0*18, N1*384, N2*768)
    float*    OutB  = (float*)alloc((size_t)12800000 * 4);   // max(N0*64, N1*128, N2*256)
    int*      colS  = (int*)alloc((size_t)EMAX * 4);
    unsigned* colB  = (unsigned*)alloc((size_t)EMAX * 4);    // single plane
    int*      ptr   = (int*)alloc((size_t)(N0 + 1) * 4);
    int*      cnt   = (int*)alloc((size_t)N0 * 4);           // reused as fallback fill
    float*    dinv  = (float*)alloc((size_t)N0 * 4);
    int*      bsum  = (int*)alloc(4096);
    float*    accum = (float*)alloc(64);                     // floats 0..9; int at +64B = dtype flag
    int*      flag  = (int*)(accum + 16);
    int*      tail  = (int*)alloc((size_t)NBUK_MAX * 4);

    detect_k<<<1, 256, 0, stream>>>((const unsigned int*)x, flag);

    const size_t NEED = 182000000;
    if (ws_size < NEED) {
        diag_k<<<1, 64, 0, stream>>>(d_out, (float)(ws_size >> 20), flag);
        return;
    }

    struct Lvl {
        int n, E, cin, cout;
        const int *rows, *cols;
        const void *w, *b;
        int relu;
    };
    Lvl L[3] = {
        {N0, E0, 3, 64, ei0, ei0 + E0, w0, b0, 1},
        {N1, E1, 64, 128, ei1, ei1 + E1, w1, b1, 1},
        {N2, E2, 128, 256, ei2, ei2 + E2, w2, b2, 0},
    };

    convert_x_k<<<(N0 * 3 + 255) / 256, 256, 0, stream>>>(x, TxAll, N0, flag);

    for (int li = 0; li < 3; ++li) {
        const Lvl& v = L[li];
        int n = v.n, E = v.E, cin = v.cin, cout = v.cout;
        int nb = (n + 255) / 256;
        int pgrid = (n + 3) / 4;
        int ld = KCH * cin;
        int nbuk = (n + BROWS - 1) >> SB;

        // CSR build (self-loops excluded => row length == deg)
        hipMemsetAsync(cnt, 0, (size_t)n * 4, stream);
        hist_k<<<(E + 255) / 256, 256, 0, stream>>>(v.rows, v.cols, cnt, E);
        dinv_k<<<nb, 256, 0, stream>>>(cnt, dinv, n);
        scan_block_k<<<nb, 256, 0, stream>>>(cnt, ptr, bsum, n);
        scan_sums_k<<<1, 1024, 0, stream>>>(bsum, nb, ptr, n);
        scan_add_k<<<nb, 256, 0, stream>>>(ptr, bsum, n);
        // two-phase binned scatter (LDS line-staged)
        tail_init_k<<<(nbuk + 255) / 256, 256, 0, stream>>>(ptr, tail, nbuk);
        {
            size_t shb = (size_t)nbuk * (QCAP + 1) * 4;
            binA_k<<<512, 256, shb, stream>>>(v.rows, v.cols, tail, colB, nbuk, E);
        }
        hipMemsetAsync(cnt, 0, (size_t)n * 4, stream);  // fallback fill (statistically unused)
        binB_k<<<nbuk, 256, 0, stream>>>(ptr, colB, colS, cnt, n);

        // Chebyshev recurrence into fused slots (slot k at column k*cin, row stride ld)
        for (int k = 1; k < KCH; ++k) {
            const float* hin = TxAll + (size_t)(k - 1) * cin;
            const float* sub = (k >= 2) ? (TxAll + (size_t)(k - 2) * cin) : nullptr;
            float* o = TxAll + (size_t)k * cin;
            float alpha = (k >= 2) ? 2.f : 1.f;
            if (cin == 3)
                prop_narrow_k<<<pgrid, 256, 0, stream>>>(ptr, colS, dinv, hin, sub, o, ld, n, alpha, k >= 2);
            else if (cin == 64)
                prop_wide_k<1><<<pgrid, 256, 0, stream>>>(ptr, colS, dinv, hin, sub, o, ld, n, alpha, k >= 2);
            else
                prop_wide_k<2><<<pgrid, 256, 0, stream>>>(ptr, colS, dinv, hin, sub, o, ld, n, alpha, k >= 2);
        }

        // fused 6-slot GEMM: OutB[n,cout] = TxAll[n,ld] @ w[ld,cout] + bias (+relu)
        dim3 gg(cout / 64, (n + 63) / 64);
        gemm_k<<<gg, 256, 0, stream>>>(TxAll, ld, v.w, 0, v.b, OutB, n, cout, ld, 4 | (v.relu ? 1 : 0), flag);

        // pool into next level's slot0
        if (li == 0)
            pool_k<<<(N1 * 64 + 255) / 256, 256, 0, stream>>>(OutB, pc0, TxAll, N1, 64, KCH * 64);
        else if (li == 1)
            pool_k<<<(N2 * 128 + 255) / 256, 256, 0, stream>>>(OutB, pc1, TxAll, N2, 128, KCH * 128);
    }

    hipMemsetAsync(accum, 0, 64, stream);
    {
        dim3 lg(128, NCLS);
        linear10_k<<<lg, 256, 0, stream>>>(OutB, lw, accum, N2 * 256, flag);
    }
    finalize_k<<<1, 64, 0, stream>>>(accum, lb, d_out, flag);
}

// Round 7
// 1685.894 us; speedup vs baseline: 1.5872x; 1.2976x over previous
//
#include <hip/hip_runtime.h>
#include <hip/hip_bf16.h>
#include <hip/hip_fp16.h>

// ChebNet classifier: 3x ChebConv(K=6) + pool + linear.
// Round 7: (1) hist-free CSR build — binA bins edges into fixed per-bucket
// slabs (tails from 0), a tiny bucket scan gives bases, and binB computes
// per-row degrees + offsets in LDS (writes ptr & dinv itself). Deletes
// hist_k's 200MB of 32B-granule atomic writes and all row-scan kernels.
// (2) Tx intermediates stored fp16 (accumulate fp32) — halves the gather
// traffic of all 15 prop dispatches, GEMM A-reads, pool writes.

#define N0 200000
#define N1 50000
#define N2 12500
#define KCH 6
#define NCLS 10

#define SB 8                 // bucket = 256 rows
#define BROWS 256
#define CAPB 14336           // per-bucket slab capacity (mean 8192, +68 sigma)
#define QCAP 19              // binA per-bucket LDS staging entries
#define NBUK_MAX 800
#define EMAX 6400000

typedef __hip_bfloat16 bf16;
typedef __half fp16;
static __device__ __forceinline__ float b2f(bf16 v) { return __bfloat162float(v); }
static __device__ __forceinline__ float blo(unsigned u) { return __uint_as_float(u << 16); }
static __device__ __forceinline__ float bhi(unsigned u) { return __uint_as_float(u & 0xFFFF0000u); }

// ---------------- dtype detection (1 = fp32, 0 = bf16) ----------------
__global__ void detect_k(const unsigned int* __restrict__ xb, int* __restrict__ flag) {
    __shared__ int cs;
    int t = threadIdx.x;
    if (t == 0) cs = 0;
    __syncthreads();
    unsigned w = xb[t];
    unsigned e = (w >> 7) & 0xFFu;
    if (e >= 0x30u && e <= 0x43u) atomicAdd(&cs, 1);
    __syncthreads();
    if (t == 0) flag[0] = (cs < 128) ? 1 : 0;
}

// ---------------- hist-free binned CSR build ----------------

// binA: bin edges into per-bucket slabs colB[b*CAPB ...]; LDS staging, 64B flushes.
// dynamic LDS: scnt[nbuk] then stage[nbuk*QCAP]
__global__ __launch_bounds__(256) void binA_k(const int* __restrict__ rows, const int* __restrict__ cols,
                                              int* __restrict__ tail, unsigned* __restrict__ colB,
                                              int nbuk, int E) {
    extern __shared__ int sh[];
    int* scnt = sh;
    int* stage = sh + nbuk;
    int t = threadIdx.x;
    for (int i = t; i < nbuk; i += 256) scnt[i] = 0;
    __syncthreads();
    int tile = (E + gridDim.x - 1) / gridDim.x;
    int beg = blockIdx.x * tile;
    int end = beg + tile;
    if (end > E) end = E;
    for (int base = beg; base < end; base += 256) {
        int idx = base + t;
        int valid = 0, b = 0;
        unsigned pk = 0;
        if (idx < end) {
            int r = rows[idx], c = cols[idx];
            if (r != c) {
                valid = 1;
                b = r >> SB;
                pk = ((unsigned)(r & (BROWS - 1)) << 18) | (unsigned)c;
            }
        }
        if (valid) {
            int slot = atomicAdd(&scnt[b], 1);
            if (slot < QCAP) stage[b * QCAP + slot] = (int)pk;
            else {  // rare spill: single-entry append
                int pos = atomicAdd(&tail[b], 1);
                if (pos < CAPB) colB[(size_t)b * CAPB + pos] = pk;
            }
        }
        __syncthreads();
        // flush full 16-entry (64B) chunks
        for (int bb = t; bb < nbuk; bb += 256) {
            int cnt2 = scnt[bb];
            if (cnt2 > QCAP) cnt2 = QCAP;
            int nf = cnt2 & ~15;
            if (nf > 0) {
                int pos = atomicAdd(&tail[bb], nf);
                if (pos + nf <= CAPB)
                    for (int i = 0; i < nf; ++i) colB[(size_t)bb * CAPB + pos + i] = (unsigned)stage[bb * QCAP + i];
                for (int i = 0; i < cnt2 - nf; ++i) stage[bb * QCAP + i] = stage[bb * QCAP + nf + i];
            }
            scnt[bb] = cnt2 - nf;
        }
        __syncthreads();
    }
    // final flush (partial chunks)
    for (int bb = t; bb < nbuk; bb += 256) {
        int cnt2 = scnt[bb];
        if (cnt2 > 0) {
            int pos = atomicAdd(&tail[bb], cnt2);
            if (pos + cnt2 <= CAPB)
                for (int i = 0; i < cnt2; ++i) colB[(size_t)bb * CAPB + pos + i] = (unsigned)stage[bb * QCAP + i];
        }
    }
}

// exclusive scan of bucket counts -> bbase; also ptr[n] = total.
__global__ __launch_bounds__(1024) void scanb_k(const int* __restrict__ tail, int* __restrict__ bbase,
                                                int nbuk, int* __restrict__ ptr, int n) {
    __shared__ int s[1024];
    int t = threadIdx.x;
    int v = 0;
    if (t < nbuk) { v = tail[t]; if (v > CAPB) v = CAPB; }
    s[t] = v;
    __syncthreads();
    for (int off = 1; off < 1024; off <<= 1) {
        int x = (t >= off) ? s[t - off] : 0;
        __syncthreads();
        s[t] += x;
        __syncthreads();
    }
    if (t < nbuk) bbase[t] = s[t] - v;
    if (t == 1023) ptr[n] = s[1023];
}

// binB: per bucket — count rows in LDS, scan, write ptr/dinv, CSR-sort slab, write colS.
__global__ __launch_bounds__(256) void binB_k(const int* __restrict__ tail, const int* __restrict__ bbase,
                                              const unsigned* __restrict__ colB,
                                              int* __restrict__ ptr, float* __restrict__ dinv,
                                              int* __restrict__ colS, int n) {
    __shared__ int lcnt[BROWS];
    __shared__ int lexc[BROWS];
    __shared__ int lfill[BROWS];
    __shared__ int scol[CAPB];
    int b = blockIdx.x;
    int t = threadIdx.x;
    int rowbase = b << SB;
    int rowend = rowbase + BROWS;
    if (rowend > n) rowend = n;
    int nrows = rowend - rowbase;
    int count = tail[b];
    if (count > CAPB) count = CAPB;
    int base = bbase[b];
    const unsigned* slab = colB + (size_t)b * CAPB;
    lcnt[t] = 0;
    lfill[t] = 0;
    __syncthreads();
    // pass 1: per-row counts
    for (int i = t; i < count; i += 256) atomicAdd(&lcnt[slab[i] >> 18], 1);
    __syncthreads();
    int v = lcnt[t];
    lexc[t] = v;
    __syncthreads();
    for (int off = 1; off < 256; off <<= 1) {
        int x = (t >= off) ? lexc[t - off] : 0;
        __syncthreads();
        lexc[t] += x;
        __syncthreads();
    }
    int excl = lexc[t] - v;
    __syncthreads();
    lexc[t] = excl;
    __syncthreads();
    if (t < nrows) {
        ptr[rowbase + t] = base + excl;
        dinv[rowbase + t] = (v > 0) ? rsqrtf((float)v) : 0.f;
    }
    // pass 2: scatter into CSR order in LDS
    for (int i = t; i < count; i += 256) {
        unsigned pk = slab[i];
        int rl = pk >> 18;
        int s = atomicAdd(&lfill[rl], 1);
        scol[lexc[rl] + s] = (int)(pk & 0x3FFFFu);
    }
    __syncthreads();
    for (int i = t; i < count; i += 256) colS[base + i] = scol[i];
}

// ---------------- feature staging ----------------

__global__ __launch_bounds__(256) void convert_x_k(const void* __restrict__ x, fp16* __restrict__ TxAll,
                                                   int n, const int* __restrict__ flag) {
    int isf = flag[0];
    int i = blockIdx.x * 256 + threadIdx.x;
    if (i >= n * 3) return;
    int r = i / 3, c = i - r * 3;
    float v;
    if (isf) v = ((const float*)x)[i];
    else     v = b2f(((const bf16*)x)[i]);
    TxAll[(size_t)r * 18 + c] = __float2half(v);
}

// ---------------- propagation (fp16 storage, fp32 accumulate) ----------------

__global__ __launch_bounds__(256) void prop_narrow_k(const int* __restrict__ ptr, const int* __restrict__ colS,
                                                     const float* __restrict__ dinv, const fp16* __restrict__ hin,
                                                     const fp16* __restrict__ sub, fp16* __restrict__ o,
                                                     int ld, int n, float alpha, int useSub) {
    int wv = threadIdx.x >> 6, lane = threadIdx.x & 63;
    int r = blockIdx.x * 4 + wv;
    if (r >= n) return;
    int s = ptr[r], e = ptr[r + 1];
    float dr = dinv[r];
    float a0 = 0.f, a1 = 0.f, a2 = 0.f;
    for (int idx = s + lane; idx < e; idx += 64) {
        int c = colS[idx];
        float nrm = -dr * dinv[c];
        const fp16* hp = hin + (size_t)c * ld;
        a0 += nrm * __half2float(hp[0]);
        a1 += nrm * __half2float(hp[1]);
        a2 += nrm * __half2float(hp[2]);
    }
    for (int off2 = 32; off2 > 0; off2 >>= 1) {
        a0 += __shfl_down(a0, off2);
        a1 += __shfl_down(a1, off2);
        a2 += __shfl_down(a2, off2);
    }
    if (lane == 0) {
        size_t b = (size_t)r * ld;
        float v0 = alpha * a0, v1 = alpha * a1, v2 = alpha * a2;
        if (useSub) {
            v0 -= __half2float(sub[b + 0]);
            v1 -= __half2float(sub[b + 1]);
            v2 -= __half2float(sub[b + 2]);
        }
        o[b + 0] = __float2half(v0);
        o[b + 1] = __float2half(v1);
        o[b + 2] = __float2half(v2);
    }
}

template <int VEC>
__global__ __launch_bounds__(256) void prop_wide_k(const int* __restrict__ ptr, const int* __restrict__ colS,
                                                   const float* __restrict__ dinv, const fp16* __restrict__ hin,
                                                   const fp16* __restrict__ sub, fp16* __restrict__ o,
                                                   int ld, int n, float alpha, int useSub) {
    int wv = threadIdx.x >> 6, lane = threadIdx.x & 63;
    int r = blockIdx.x * 4 + wv;
    if (r >= n) return;
    int s = ptr[r], e = ptr[r + 1];
    float dr = dinv[r];
    float acc[VEC];
#pragma unroll
    for (int v = 0; v < VEC; ++v) acc[v] = 0.f;
    for (int base = s; base < e; base += 64) {
        int idx = base + lane;
        int c = 0;
        float dc = 0.f;
        if (idx < e) { c = colS[idx]; dc = dinv[c]; }
        int cnt2 = e - base;
        if (cnt2 > 64) cnt2 = 64;
        int j = 0;
        for (; j + 4 <= cnt2; j += 4) {
            int cc0 = __shfl(c, j), cc1 = __shfl(c, j + 1), cc2 = __shfl(c, j + 2), cc3 = __shfl(c, j + 3);
            float n0 = -dr * __shfl(dc, j), n1 = -dr * __shfl(dc, j + 1);
            float n2 = -dr * __shfl(dc, j + 2), n3 = -dr * __shfl(dc, j + 3);
            const fp16* h0 = hin + (size_t)cc0 * ld + lane;
            const fp16* h1 = hin + (size_t)cc1 * ld + lane;
            const fp16* h2 = hin + (size_t)cc2 * ld + lane;
            const fp16* h3 = hin + (size_t)cc3 * ld + lane;
            float v0[VEC], v1[VEC], v2[VEC], v3[VEC];
#pragma unroll
            for (int v = 0; v < VEC; ++v) {
                v0[v] = __half2float(h0[v * 64]);
                v1[v] = __half2float(h1[v * 64]);
                v2[v] = __half2float(h2[v * 64]);
                v3[v] = __half2float(h3[v * 64]);
            }
#pragma unroll
            for (int v = 0; v < VEC; ++v) acc[v] += n0 * v0[v] + n1 * v1[v] + n2 * v2[v] + n3 * v3[v];
        }
        for (; j < cnt2; ++j) {
            int cc = __shfl(c, j);
            float nrm = -dr * __shfl(dc, j);
            const fp16* hp = hin + (size_t)cc * ld + lane;
#pragma unroll
            for (int v = 0; v < VEC; ++v) acc[v] += nrm * __half2float(hp[v * 64]);
        }
    }
    size_t rb = (size_t)r * ld + lane;
#pragma unroll
    for (int v = 0; v < VEC; ++v) {
        float val = alpha * acc[v];
        if (useSub) val -= __half2float(sub[rb + v * 64]);
        o[rb + v * 64] = __float2half(val);
    }
}

// ---------------- GEMM: C = A(fp16) @ W [+ bias] [relu] ----------------
// flags: 1 = relu, 4 = add bias.

__global__ __launch_bounds__(256) void gemm_k(const fp16* __restrict__ A, int lda,
                                              const void* __restrict__ W,
                                              const void* __restrict__ bias,
                                              float* __restrict__ C, int M, int N, int K, int flags,
                                              const int* __restrict__ flag) {
    __shared__ float As[16][65];
    __shared__ float Ws[16][64];
    int isf = flag[0];
    int t = threadIdx.x;
    int tn = t & 15, tm = t >> 4;
    int m0 = blockIdx.y * 64, n0 = blockIdx.x * 64;
    float acc[4][4] = {};
    for (int k0 = 0; k0 < K; k0 += 16) {
#pragma unroll
        for (int i = 0; i < 4; ++i) {
            int idx = i * 256 + t;
            int m = idx >> 4, k = idx & 15;
            int gm = m0 + m, gk = k0 + k;
            As[k][m] = (gm < M && gk < K) ? __half2float(A[(size_t)gm * lda + gk]) : 0.f;
        }
        if (isf) {
            const float* Wf = (const float*)W;
#pragma unroll
            for (int i = 0; i < 4; ++i) {
                int idx = i * 256 + t;
                int k = idx >> 6, nn = idx & 63;
                int gk = k0 + k;
                Ws[k][nn] = (gk < K) ? Wf[(size_t)gk * N + n0 + nn] : 0.f;
            }
        } else {
            const bf16* Wh = (const bf16*)W;
#pragma unroll
            for (int i = 0; i < 4; ++i) {
                int idx = i * 256 + t;
                int k = idx >> 6, nn = idx & 63;
                int gk = k0 + k;
                Ws[k][nn] = (gk < K) ? b2f(Wh[(size_t)gk * N + n0 + nn]) : 0.f;
            }
        }
        __syncthreads();
#pragma unroll
        for (int kk = 0; kk < 16; ++kk) {
            float a[4], b[4];
#pragma unroll
            for (int i = 0; i < 4; ++i) a[i] = As[kk][tm * 4 + i];
#pragma unroll
            for (int j = 0; j < 4; ++j) b[j] = Ws[kk][tn * 4 + j];
#pragma unroll
            for (int i = 0; i < 4; ++i)
#pragma unroll
                for (int j = 0; j < 4; ++j) acc[i][j] += a[i] * b[j];
        }
        __syncthreads();
    }
#pragma unroll
    for (int i = 0; i < 4; ++i) {
        int gm = m0 + tm * 4 + i;
        if (gm >= M) continue;
#pragma unroll
        for (int j = 0; j < 4; ++j) {
            int gn = n0 + tn * 4 + j;
            size_t ci = (size_t)gm * N + gn;
            float v = acc[i][j];
            if (flags & 4) {
                if (isf) v += ((const float*)bias)[gn];
                else     v += b2f(((const bf16*)bias)[gn]);
            }
            if (flags & 1) v = fmaxf(v, 0.f);
            C[ci] = v;
        }
    }
}

// ---------------- pooling (fp32 in -> fp16 out into next level slot0) ----------------

__global__ __launch_bounds__(256) void pool_k(const float* __restrict__ in, const int* __restrict__ pcols,
                                              fp16* __restrict__ out, int n_out, int C, int ld) {
    int idx = blockIdx.x * 256 + threadIdx.x;
    if (idx >= n_out * C) return;
    int r = idx / C, ch = idx - r * C;
    const int* pc = pcols + (size_t)r * 4;
    float ssum = 0.f;
#pragma unroll
    for (int f = 0; f < 4; ++f) ssum += in[(size_t)pc[f] * C + ch];
    out[(size_t)r * ld + ch] = __float2half(0.25f * ssum);
}

// ---------------- final linear ----------------

__global__ __launch_bounds__(256) void linear10_k(const float* __restrict__ h, const void* __restrict__ lw,
                                                  float* __restrict__ accum, int LIN, const int* __restrict__ flag) {
    int isf = flag[0];
    int c = blockIdx.y;
    int t = threadIdx.x;
    int nvec = LIN >> 3;
    int stride = gridDim.x * 256;
    float p = 0.f;
    const float4* h4 = (const float4*)h;
    if (isf) {
        const float4* lw4 = (const float4*)lw + (size_t)c * (LIN >> 2);
        for (int i = blockIdx.x * 256 + t; i < nvec; i += stride) {
            float4 a0 = h4[2 * i], a1 = h4[2 * i + 1];
            float4 b0 = lw4[2 * i], b1 = lw4[2 * i + 1];
            p += a0.x * b0.x + a0.y * b0.y + a0.z * b0.z + a0.w * b0.w
               + a1.x * b1.x + a1.y * b1.y + a1.z * b1.z + a1.w * b1.w;
        }
    } else {
        const uint4* lwv = (const uint4*)lw + (size_t)c * nvec;
        for (int i = blockIdx.x * 256 + t; i < nvec; i += stride) {
            uint4 w4 = lwv[i];
            float4 a0 = h4[2 * i], a1 = h4[2 * i + 1];
            p += a0.x * blo(w4.x) + a0.y * bhi(w4.x)
               + a0.z * blo(w4.y) + a0.w * bhi(w4.y)
               + a1.x * blo(w4.z) + a1.y * bhi(w4.z)
               + a1.z * blo(w4.w) + a1.w * bhi(w4.w);
        }
    }
    for (int off2 = 32; off2 > 0; off2 >>= 1) p += __shfl_down(p, off2);
    __shared__ float wsum[4];
    int wv = t >> 6, lane = t & 63;
    if (lane == 0) wsum[wv] = p;
    __syncthreads();
    if (t == 0) unsafeAtomicAdd(&accum[c], wsum[0] + wsum[1] + wsum[2] + wsum[3]);
}

__global__ void finalize_k(const float* __restrict__ accum, const void* __restrict__ lb,
                           void* __restrict__ outp, const int* __restrict__ flag) {
    int isf = flag[0];
    int t = threadIdx.x;
    if (t < NCLS) {
        float lbv;
        if (isf) lbv = ((const float*)lb)[t];
        else     lbv = b2f(((const bf16*)lb)[t]);
        float v = accum[t] + lbv;
        if (isf) ((float*)outp)[t] = v;
        else     ((bf16*)outp)[t] = __float2bfloat16(v);
    }
}

__global__ void diag_k(void* __restrict__ outp, float val, const int* __restrict__ flag) {
    int isf = flag[0];
    int t = threadIdx.x;
    if (t < NCLS) {
        if (isf) ((float*)outp)[t] = val;
        else     ((bf16*)outp)[t] = __float2bfloat16(val);
    }
}

// ---------------- orchestration ----------------

extern "C" void kernel_launch(void* const* d_in, const int* in_sizes, int n_in,
                              void* d_out, int out_size, void* d_ws, size_t ws_size,
                              hipStream_t stream) {
    const void* x  = d_in[0];
    const int* ei0 = (const int*)d_in[1];
    const int* ei1 = (const int*)d_in[2];
    const int* ei2 = (const int*)d_in[3];
    const int* pc0 = (const int*)d_in[4];
    const int* pc1 = (const int*)d_in[5];
    const void* w0 = d_in[6];
    const void* b0 = d_in[7];
    const void* w1 = d_in[8];
    const void* b1 = d_in[9];
    const void* w2 = d_in[10];
    const void* b2 = d_in[11];
    const void* lw = d_in[12];
    const void* lb = d_in[13];

    const int E0 = in_sizes[1] / 2, E1 = in_sizes[2] / 2, E2 = in_sizes[3] / 2;

    // ---- workspace layout (~167 MB; ws is ~512 MB per harness poison) ----
    char* base = (char*)d_ws;
    size_t off = 0;
    auto alloc = [&](size_t bytes) -> void* {
        void* p = base + off;
        off += (bytes + 255) & ~(size_t)255;
        return p;
    };
    fp16*     TxAll = (fp16*)alloc((size_t)19200000 * 2);    // max(N0*18, N1*384, N2*768), fp16
    float*    OutB  = (float*)alloc((size_t)12800000 * 4);   // max(N0*64, N1*128, N2*256)
    int*      colS  = (int*)alloc((size_t)EMAX * 4);
    unsigned* colB  = (unsigned*)alloc((size_t)NBUK_MAX * CAPB * 4);  // bucket slabs
    int*      ptr   = (int*)alloc((size_t)(N0 + 1) * 4);
    float*    dinv  = (float*)alloc((size_t)N0 * 4);
    int*      tail  = (int*)alloc((size_t)NBUK_MAX * 4);
    int*      bbase = (int*)alloc((size_t)NBUK_MAX * 4);
    float*    accum = (float*)alloc(64);                     // floats 0..9; int at +64B = dtype flag
    int*      flag  = (int*)(accum + 16);

    detect_k<<<1, 256, 0, stream>>>((const unsigned int*)x, flag);

    const size_t NEED = 167000000;
    if (ws_size < NEED) {
        diag_k<<<1, 64, 0, stream>>>(d_out, (float)(ws_size >> 20), flag);
        return;
    }

    struct Lvl {
        int n, E, cin, cout;
        const int *rows, *cols;
        const void *w, *b;
        int relu;
    };
    Lvl L[3] = {
        {N0, E0, 3, 64, ei0, ei0 + E0, w0, b0, 1},
        {N1, E1, 64, 128, ei1, ei1 + E1, w1, b1, 1},
        {N2, E2, 128, 256, ei2, ei2 + E2, w2, b2, 0},
    };

    convert_x_k<<<(N0 * 3 + 255) / 256, 256, 0, stream>>>(x, TxAll, N0, flag);

    for (int li = 0; li < 3; ++li) {
        const Lvl& v = L[li];
        int n = v.n, E = v.E, cin = v.cin, cout = v.cout;
        int pgrid = (n + 3) / 4;
        int ld = KCH * cin;
        int nbuk = (n + BROWS - 1) >> SB;

        // hist-free binned CSR build (writes ptr, dinv, colS)
        hipMemsetAsync(tail, 0, (size_t)nbuk * 4, stream);
        {
            size_t shb = (size_t)nbuk * (QCAP + 1) * 4;
            binA_k<<<512, 256, shb, stream>>>(v.rows, v.cols, tail, colB, nbuk, E);
        }
        scanb_k<<<1, 1024, 0, stream>>>(tail, bbase, nbuk, ptr, n);
        binB_k<<<nbuk, 256, 0, stream>>>(tail, bbase, colB, ptr, dinv, colS, n);

        // Chebyshev recurrence into fused slots (slot k at column k*cin, row stride ld)
        for (int k = 1; k < KCH; ++k) {
            const fp16* hin = TxAll + (size_t)(k - 1) * cin;
            const fp16* sub = (k >= 2) ? (TxAll + (size_t)(k - 2) * cin) : nullptr;
            fp16* o = TxAll + (size_t)k * cin;
            float alpha = (k >= 2) ? 2.f : 1.f;
            if (cin == 3)
                prop_narrow_k<<<pgrid, 256, 0, stream>>>(ptr, colS, dinv, hin, sub, o, ld, n, alpha, k >= 2);
            else if (cin == 64)
                prop_wide_k<1><<<pgrid, 256, 0, stream>>>(ptr, colS, dinv, hin, sub, o, ld, n, alpha, k >= 2);
            else
                prop_wide_k<2><<<pgrid, 256, 0, stream>>>(ptr, colS, dinv, hin, sub, o, ld, n, alpha, k >= 2);
        }

        // fused 6-slot GEMM: OutB[n,cout] = TxAll[n,ld] @ w[ld,cout] + bias (+relu)
        dim3 gg(cout / 64, (n + 63) / 64);
        gemm_k<<<gg, 256, 0, stream>>>(TxAll, ld, v.w, v.b, OutB, n, cout, ld, 4 | (v.relu ? 1 : 0), flag);

        // pool into next level's slot0
        if (li == 0)
            pool_k<<<(N1 * 64 + 255) / 256, 256, 0, stream>>>(OutB, pc0, TxAll, N1, 64, KCH * 64);
        else if (li == 1)
            pool_k<<<(N2 * 128 + 255) / 256, 256, 0, stream>>>(OutB, pc1, TxAll, N2, 128, KCH * 128);
    }

    hipMemsetAsync(accum, 0, 64, stream);
    {
        dim3 lg(128, NCLS);
        linear10_k<<<lg, 256, 0, stream>>>(OutB, lw, accum, N2 * 256, flag);
    }
    finalize_k<<<1, 64, 0, stream>>>(accum, lb, d_out, flag);
}

// Round 8
// 1384.197 us; speedup vs baseline: 1.9331x; 1.2180x over previous
//
#include <hip/hip_runtime.h>
#include <hip/hip_bf16.h>

// ChebNet classifier: 3x ChebConv(K=6) + pool + linear.
// Round 8: (1) MFMA (16x16x32 f16) GEMM for levels 1/2 — 64x64 tile, 4 waves,
// A fp16 from TxAll, W bf16->fp16 in LDS staging; (2) L0 rows packed as
// [h0,h1,h2,dinv] fp16x4 -> one 8B gather per edge (was 4 transactions);
// (3) wide props use half2 loads (L1: 2 edges/step across half-waves).

#define N0 200000
#define N1 50000
#define N2 12500
#define KCH 6
#define NCLS 10

#define SB 8                 // bucket = 256 rows
#define BROWS 256
#define CAPB 14336           // per-bucket slab capacity (mean 8192, +68 sigma)
#define QCAP 19              // binA per-bucket LDS staging entries
#define NBUK_MAX 800
#define EMAX 6400000

typedef __hip_bfloat16 bf16;
typedef _Float16 f16;
typedef f16 f16x2 __attribute__((ext_vector_type(2)));
typedef f16 f16x4 __attribute__((ext_vector_type(4)));
typedef f16 f16x8 __attribute__((ext_vector_type(8)));
typedef float f32x4 __attribute__((ext_vector_type(4)));

static __device__ __forceinline__ float b2f(bf16 v) { return __bfloat162float(v); }
static __device__ __forceinline__ float blo(unsigned u) { return __uint_as_float(u << 16); }
static __device__ __forceinline__ float bhi(unsigned u) { return __uint_as_float(u & 0xFFFF0000u); }

// ---------------- dtype detection (1 = fp32, 0 = bf16) ----------------
__global__ void detect_k(const unsigned int* __restrict__ xb, int* __restrict__ flag) {
    __shared__ int cs;
    int t = threadIdx.x;
    if (t == 0) cs = 0;
    __syncthreads();
    unsigned w = xb[t];
    unsigned e = (w >> 7) & 0xFFu;
    if (e >= 0x30u && e <= 0x43u) atomicAdd(&cs, 1);
    __syncthreads();
    if (t == 0) flag[0] = (cs < 128) ? 1 : 0;
}

// ---------------- hist-free binned CSR build ----------------

__global__ __launch_bounds__(256) void binA_k(const int* __restrict__ rows, const int* __restrict__ cols,
                                              int* __restrict__ tail, unsigned* __restrict__ colB,
                                              int nbuk, int E) {
    extern __shared__ int sh[];
    int* scnt = sh;
    int* stage = sh + nbuk;
    int t = threadIdx.x;
    for (int i = t; i < nbuk; i += 256) scnt[i] = 0;
    __syncthreads();
    int tile = (E + gridDim.x - 1) / gridDim.x;
    int beg = blockIdx.x * tile;
    int end = beg + tile;
    if (end > E) end = E;
    for (int base = beg; base < end; base += 256) {
        int idx = base + t;
        int valid = 0, b = 0;
        unsigned pk = 0;
        if (idx < end) {
            int r = rows[idx], c = cols[idx];
            if (r != c) {
                valid = 1;
                b = r >> SB;
                pk = ((unsigned)(r & (BROWS - 1)) << 18) | (unsigned)c;
            }
        }
        if (valid) {
            int slot = atomicAdd(&scnt[b], 1);
            if (slot < QCAP) stage[b * QCAP + slot] = (int)pk;
            else {
                int pos = atomicAdd(&tail[b], 1);
                if (pos < CAPB) colB[(size_t)b * CAPB + pos] = pk;
            }
        }
        __syncthreads();
        for (int bb = t; bb < nbuk; bb += 256) {
            int cnt2 = scnt[bb];
            if (cnt2 > QCAP) cnt2 = QCAP;
            int nf = cnt2 & ~15;
            if (nf > 0) {
                int pos = atomicAdd(&tail[bb], nf);
                if (pos + nf <= CAPB)
                    for (int i = 0; i < nf; ++i) colB[(size_t)bb * CAPB + pos + i] = (unsigned)stage[bb * QCAP + i];
                for (int i = 0; i < cnt2 - nf; ++i) stage[bb * QCAP + i] = stage[bb * QCAP + nf + i];
            }
            scnt[bb] = cnt2 - nf;
        }
        __syncthreads();
    }
    for (int bb = t; bb < nbuk; bb += 256) {
        int cnt2 = scnt[bb];
        if (cnt2 > 0) {
            int pos = atomicAdd(&tail[bb], cnt2);
            if (pos + cnt2 <= CAPB)
                for (int i = 0; i < cnt2; ++i) colB[(size_t)bb * CAPB + pos + i] = (unsigned)stage[bb * QCAP + i];
        }
    }
}

__global__ __launch_bounds__(1024) void scanb_k(const int* __restrict__ tail, int* __restrict__ bbase,
                                                int nbuk, int* __restrict__ ptr, int n) {
    __shared__ int s[1024];
    int t = threadIdx.x;
    int v = 0;
    if (t < nbuk) { v = tail[t]; if (v > CAPB) v = CAPB; }
    s[t] = v;
    __syncthreads();
    for (int off = 1; off < 1024; off <<= 1) {
        int x = (t >= off) ? s[t - off] : 0;
        __syncthreads();
        s[t] += x;
        __syncthreads();
    }
    if (t < nbuk) bbase[t] = s[t] - v;
    if (t == 1023) ptr[n] = s[1023];
}

__global__ __launch_bounds__(256) void binB_k(const int* __restrict__ tail, const int* __restrict__ bbase,
                                              const unsigned* __restrict__ colB,
                                              int* __restrict__ ptr, float* __restrict__ dinv,
                                              int* __restrict__ colS, int n) {
    __shared__ int lcnt[BROWS];
    __shared__ int lexc[BROWS];
    __shared__ int lfill[BROWS];
    __shared__ int scol[CAPB];
    int b = blockIdx.x;
    int t = threadIdx.x;
    int rowbase = b << SB;
    int rowend = rowbase + BROWS;
    if (rowend > n) rowend = n;
    int nrows = rowend - rowbase;
    int count = tail[b];
    if (count > CAPB) count = CAPB;
    int base = bbase[b];
    const unsigned* slab = colB + (size_t)b * CAPB;
    lcnt[t] = 0;
    lfill[t] = 0;
    __syncthreads();
    for (int i = t; i < count; i += 256) atomicAdd(&lcnt[slab[i] >> 18], 1);
    __syncthreads();
    int v = lcnt[t];
    lexc[t] = v;
    __syncthreads();
    for (int off = 1; off < 256; off <<= 1) {
        int x = (t >= off) ? lexc[t - off] : 0;
        __syncthreads();
        lexc[t] += x;
        __syncthreads();
    }
    int excl = lexc[t] - v;
    __syncthreads();
    lexc[t] = excl;
    __syncthreads();
    if (t < nrows) {
        ptr[rowbase + t] = base + excl;
        dinv[rowbase + t] = (v > 0) ? rsqrtf((float)v) : 0.f;
    }
    for (int i = t; i < count; i += 256) {
        unsigned pk = slab[i];
        int rl = pk >> 18;
        int s = atomicAdd(&lfill[rl], 1);
        scol[lexc[rl] + s] = (int)(pk & 0x3FFFFu);
    }
    __syncthreads();
    for (int i = t; i < count; i += 256) colS[base + i] = scol[i];
}

// ---------------- feature staging: x -> packed [h0,h1,h2,dinv] (ld=24) ----------------

__global__ __launch_bounds__(256) void convert_x_k(const void* __restrict__ x, f16* __restrict__ Tx,
                                                   const float* __restrict__ dinv, int n,
                                                   const int* __restrict__ flag) {
    int isf = flag[0];
    int r = blockIdx.x * 256 + threadIdx.x;
    if (r >= n) return;
    float v0, v1, v2;
    if (isf) {
        const float* xf = (const float*)x;
        v0 = xf[3 * r]; v1 = xf[3 * r + 1]; v2 = xf[3 * r + 2];
    } else {
        const bf16* xh = (const bf16*)x;
        v0 = b2f(xh[3 * r]); v1 = b2f(xh[3 * r + 1]); v2 = b2f(xh[3 * r + 2]);
    }
    f16x4 pk = {(f16)v0, (f16)v1, (f16)v2, (f16)dinv[r]};
    *(f16x4*)(Tx + (size_t)r * 24) = pk;
}

// ---------------- propagation ----------------

// L0: packed rows, one 8B gather per edge (h0,h1,h2,dinv).
__global__ __launch_bounds__(256) void prop_narrow_k(const int* __restrict__ ptr, const int* __restrict__ colS,
                                                     const float* __restrict__ dinv, const f16* __restrict__ hin,
                                                     const f16* __restrict__ sub, f16* __restrict__ o,
                                                     int n, float alpha, int useSub) {
    int wv = threadIdx.x >> 6, lane = threadIdx.x & 63;
    int r = blockIdx.x * 4 + wv;
    if (r >= n) return;
    int s = ptr[r], e = ptr[r + 1];
    float dr = dinv[r];
    float a0 = 0.f, a1 = 0.f, a2 = 0.f;
    for (int idx = s + lane; idx < e; idx += 64) {
        int c = colS[idx];
        f16x4 h = *(const f16x4*)(hin + (size_t)c * 24);
        float nrm = -dr * (float)h.w;
        a0 += nrm * (float)h.x;
        a1 += nrm * (float)h.y;
        a2 += nrm * (float)h.z;
    }
    for (int off2 = 32; off2 > 0; off2 >>= 1) {
        a0 += __shfl_down(a0, off2);
        a1 += __shfl_down(a1, off2);
        a2 += __shfl_down(a2, off2);
    }
    if (lane == 0) {
        float v0 = alpha * a0, v1 = alpha * a1, v2 = alpha * a2;
        if (useSub) {
            f16x4 sv = *(const f16x4*)(sub + (size_t)r * 24);
            v0 -= (float)sv.x; v1 -= (float)sv.y; v2 -= (float)sv.z;
        }
        f16x4 ov = {(f16)v0, (f16)v1, (f16)v2, (f16)dr};
        *(f16x4*)(o + (size_t)r * 24) = ov;
    }
}

// L1 (cin=64): half-wave p handles edge j+p; lane q covers channel pair 2q via half2.
__global__ __launch_bounds__(256) void prop_wide2_k(const int* __restrict__ ptr, const int* __restrict__ colS,
                                                    const float* __restrict__ dinv, const f16* __restrict__ hin,
                                                    const f16* __restrict__ sub, f16* __restrict__ o,
                                                    int ld, int n, float alpha, int useSub) {
    int wv = threadIdx.x >> 6, lane = threadIdx.x & 63;
    int p = lane >> 5, q = lane & 31;
    int r = blockIdx.x * 4 + wv;
    if (r >= n) return;
    int s = ptr[r], e = ptr[r + 1];
    float dr = dinv[r];
    float ax = 0.f, ay = 0.f;
    for (int base = s; base < e; base += 64) {
        int idx = base + lane;
        int c = 0;
        float dc = 0.f;
        if (idx < e) { c = colS[idx]; dc = dinv[c]; }
        int cnt2 = e - base;
        if (cnt2 > 64) cnt2 = 64;
        int j = 0;
        for (; j + 4 <= cnt2; j += 4) {
            int j0 = j + p, j1 = j + 2 + p;
            int c0 = __shfl(c, j0), c1 = __shfl(c, j1);
            float n0 = -dr * __shfl(dc, j0), n1 = -dr * __shfl(dc, j1);
            f16x2 h0 = *(const f16x2*)(hin + (size_t)c0 * ld + 2 * q);
            f16x2 h1 = *(const f16x2*)(hin + (size_t)c1 * ld + 2 * q);
            ax += n0 * (float)h0.x + n1 * (float)h1.x;
            ay += n0 * (float)h0.y + n1 * (float)h1.y;
        }
        for (; j < cnt2; j += 2) {
            int jj = j + p;
            int valid = jj < cnt2;
            int cc = __shfl(c, valid ? jj : 0);
            float nd = __shfl(dc, valid ? jj : 0);
            float nrm = valid ? -dr * nd : 0.f;
            f16x2 h = *(const f16x2*)(hin + (size_t)cc * ld + 2 * q);
            ax += nrm * (float)h.x;
            ay += nrm * (float)h.y;
        }
    }
    ax += __shfl_xor(ax, 32);
    ay += __shfl_xor(ay, 32);
    if (p == 0) {
        size_t rb = (size_t)r * ld + 2 * q;
        float vx = alpha * ax, vy = alpha * ay;
        if (useSub) {
            f16x2 sv = *(const f16x2*)(sub + rb);
            vx -= (float)sv.x; vy -= (float)sv.y;
        }
        f16x2 ov = {(f16)vx, (f16)vy};
        *(f16x2*)(o + rb) = ov;
    }
}

// L2 (cin=128): lane covers channel pair 2*lane via half2; one edge/step, x4 unroll.
__global__ __launch_bounds__(256) void prop_wide1h_k(const int* __restrict__ ptr, const int* __restrict__ colS,
                                                     const float* __restrict__ dinv, const f16* __restrict__ hin,
                                                     const f16* __restrict__ sub, f16* __restrict__ o,
                                                     int ld, int n, float alpha, int useSub) {
    int wv = threadIdx.x >> 6, lane = threadIdx.x & 63;
    int r = blockIdx.x * 4 + wv;
    if (r >= n) return;
    int s = ptr[r], e = ptr[r + 1];
    float dr = dinv[r];
    float ax = 0.f, ay = 0.f;
    for (int base = s; base < e; base += 64) {
        int idx = base + lane;
        int c = 0;
        float dc = 0.f;
        if (idx < e) { c = colS[idx]; dc = dinv[c]; }
        int cnt2 = e - base;
        if (cnt2 > 64) cnt2 = 64;
        int j = 0;
        for (; j + 4 <= cnt2; j += 4) {
            int c0 = __shfl(c, j), c1 = __shfl(c, j + 1), c2 = __shfl(c, j + 2), c3 = __shfl(c, j + 3);
            float n0 = -dr * __shfl(dc, j), n1 = -dr * __shfl(dc, j + 1);
            float n2 = -dr * __shfl(dc, j + 2), n3 = -dr * __shfl(dc, j + 3);
            f16x2 h0 = *(const f16x2*)(hin + (size_t)c0 * ld + 2 * lane);
            f16x2 h1 = *(const f16x2*)(hin + (size_t)c1 * ld + 2 * lane);
            f16x2 h2 = *(const f16x2*)(hin + (size_t)c2 * ld + 2 * lane);
            f16x2 h3 = *(const f16x2*)(hin + (size_t)c3 * ld + 2 * lane);
            ax += n0 * (float)h0.x + n1 * (float)h1.x + n2 * (float)h2.x + n3 * (float)h3.x;
            ay += n0 * (float)h0.y + n1 * (float)h1.y + n2 * (float)h2.y + n3 * (float)h3.y;
        }
        for (; j < cnt2; ++j) {
            int cc = __shfl(c, j);
            float nrm = -dr * __shfl(dc, j);
            f16x2 h = *(const f16x2*)(hin + (size_t)cc * ld + 2 * lane);
            ax += nrm * (float)h.x;
            ay += nrm * (float)h.y;
        }
    }
    size_t rb = (size_t)r * ld + 2 * lane;
    float vx = alpha * ax, vy = alpha * ay;
    if (useSub) {
        f16x2 sv = *(const f16x2*)(sub + rb);
        vx -= (float)sv.x; vy -= (float)sv.y;
    }
    f16x2 ov = {(f16)vx, (f16)vy};
    *(f16x2*)(o + rb) = ov;
}

// ---------------- MFMA GEMM (L1/L2): C = A(fp16)@W + bias (+relu) ----------------
// 64x64 tile, 4 waves; wave w: rows 16w..16w+15, 4 col-tiles of 16. K%32==0.
// Layouts (guide-verified): A[m=lane&15][k=quad*8+j]; B[k=quad*8+j][n=lane&15];
// C/D row=quad*4+reg, col=lane&15.

__global__ __launch_bounds__(256) void gemm_mfma_k(const f16* __restrict__ A, int lda,
                                                   const void* __restrict__ W, const void* __restrict__ bias,
                                                   float* __restrict__ C, int M, int N, int K, int flags,
                                                   const int* __restrict__ flag) {
    __shared__ f16 As[64][40];
    __shared__ f16 Bs[64][40];
    int isf = flag[0];
    int t = threadIdx.x;
    int w = t >> 6, l = t & 63, q = l >> 4, m16 = l & 15;
    int m0 = blockIdx.y * 64, n0 = blockIdx.x * 64;
    f32x4 acc[4] = {};
    for (int k0 = 0; k0 < K; k0 += 32) {
        {   // A stage: 64 rows x 32 halves
            int row = t >> 2, cg = (t & 3) * 8;
            int gm = m0 + row;
            f16x8 av = {};
            if (gm < M) av = *(const f16x8*)(A + (size_t)gm * lda + k0 + cg);
            *(f16x8*)&As[row][cg] = av;
        }
        {   // B stage (transposed): Bs[n][k] = W[k0+kk][n0+nb+i]
            int kk = t >> 3, nb = (t & 7) * 8;
            float wv[8];
            if (isf) {
                const float* Wf = (const float*)W + (size_t)(k0 + kk) * N + n0 + nb;
#pragma unroll
                for (int i = 0; i < 8; ++i) wv[i] = Wf[i];
            } else {
                const bf16* Wh = (const bf16*)W + (size_t)(k0 + kk) * N + n0 + nb;
#pragma unroll
                for (int i = 0; i < 8; ++i) wv[i] = b2f(Wh[i]);
            }
#pragma unroll
            for (int i = 0; i < 8; ++i) Bs[nb + i][kk] = (f16)wv[i];
        }
        __syncthreads();
        f16x8 a = *(const f16x8*)&As[w * 16 + m16][q * 8];
        f16x8 b0 = *(const f16x8*)&Bs[m16][q * 8];
        f16x8 b1 = *(const f16x8*)&Bs[16 + m16][q * 8];
        f16x8 b2 = *(const f16x8*)&Bs[32 + m16][q * 8];
        f16x8 b3 = *(const f16x8*)&Bs[48 + m16][q * 8];
        acc[0] = __builtin_amdgcn_mfma_f32_16x16x32_f16(a, b0, acc[0], 0, 0, 0);
        acc[1] = __builtin_amdgcn_mfma_f32_16x16x32_f16(a, b1, acc[1], 0, 0, 0);
        acc[2] = __builtin_amdgcn_mfma_f32_16x16x32_f16(a, b2, acc[2], 0, 0, 0);
        acc[3] = __builtin_amdgcn_mfma_f32_16x16x32_f16(a, b3, acc[3], 0, 0, 0);
        __syncthreads();
    }
#pragma unroll
    for (int tile = 0; tile < 4; ++tile) {
        int gn = n0 + tile * 16 + m16;
        float bv = 0.f;
        if (flags & 4) {
            if (isf) bv = ((const float*)bias)[gn];
            else     bv = b2f(((const bf16*)bias)[gn]);
        }
#pragma unroll
        for (int i = 0; i < 4; ++i) {
            int gm = m0 + w * 16 + q * 4 + i;
            if (gm < M) {
                float v = acc[tile][i] + bv;
                if (flags & 1) v = fmaxf(v, 0.f);
                C[(size_t)gm * N + gn] = v;
            }
        }
    }
}

// ---------------- vector GEMM (L0 only; packed-A mapping phys = gk + gk/3) ----------------
// flags: 1 = relu, 4 = bias, 8 = pack3

__global__ __launch_bounds__(256) void gemm_k(const f16* __restrict__ A, int lda,
                                              const void* __restrict__ W,
                                              const void* __restrict__ bias,
                                              float* __restrict__ C, int M, int N, int K, int flags,
                                              const int* __restrict__ flag) {
    __shared__ float As[16][65];
    __shared__ float Ws[16][64];
    int isf = flag[0];
    int pack3 = flags & 8;
    int t = threadIdx.x;
    int tn = t & 15, tm = t >> 4;
    int m0 = blockIdx.y * 64, n0 = blockIdx.x * 64;
    float acc[4][4] = {};
    for (int k0 = 0; k0 < K; k0 += 16) {
#pragma unroll
        for (int i = 0; i < 4; ++i) {
            int idx = i * 256 + t;
            int m = idx >> 4, k = idx & 15;
            int gm = m0 + m, gk = k0 + k;
            int phys = pack3 ? (gk + gk / 3) : gk;
            As[k][m] = (gm < M && gk < K) ? (float)A[(size_t)gm * lda + phys] : 0.f;
        }
        if (isf) {
            const float* Wf = (const float*)W;
#pragma unroll
            for (int i = 0; i < 4; ++i) {
                int idx = i * 256 + t;
                int k = idx >> 6, nn = idx & 63;
                int gk = k0 + k;
                Ws[k][nn] = (gk < K) ? Wf[(size_t)gk * N + n0 + nn] : 0.f;
            }
        } else {
            const bf16* Wh = (const bf16*)W;
#pragma unroll
            for (int i = 0; i < 4; ++i) {
                int idx = i * 256 + t;
                int k = idx >> 6, nn = idx & 63;
                int gk = k0 + k;
                Ws[k][nn] = (gk < K) ? b2f(Wh[(size_t)gk * N + n0 + nn]) : 0.f;
            }
        }
        __syncthreads();
#pragma unroll
        for (int kk = 0; kk < 16; ++kk) {
            float a[4], b[4];
#pragma unroll
            for (int i = 0; i < 4; ++i) a[i] = As[kk][tm * 4 + i];
#pragma unroll
            for (int j = 0; j < 4; ++j) b[j] = Ws[kk][tn * 4 + j];
#pragma unroll
            for (int i = 0; i < 4; ++i)
#pragma unroll
                for (int j = 0; j < 4; ++j) acc[i][j] += a[i] * b[j];
        }
        __syncthreads();
    }
#pragma unroll
    for (int i = 0; i < 4; ++i) {
        int gm = m0 + tm * 4 + i;
        if (gm >= M) continue;
#pragma unroll
        for (int j = 0; j < 4; ++j) {
            int gn = n0 + tn * 4 + j;
            size_t ci = (size_t)gm * N + gn;
            float v = acc[i][j];
            if (flags & 4) {
                if (isf) v += ((const float*)bias)[gn];
                else     v += b2f(((const bf16*)bias)[gn]);
            }
            if (flags & 1) v = fmaxf(v, 0.f);
            C[ci] = v;
        }
    }
}

// ---------------- pooling (fp32 in -> fp16 out into next level slot0) ----------------

__global__ __launch_bounds__(256) void pool_k(const float* __restrict__ in, const int* __restrict__ pcols,
                                              f16* __restrict__ out, int n_out, int C, int ld) {
    int idx = blockIdx.x * 256 + threadIdx.x;
    if (idx >= n_out * C) return;
    int r = idx / C, ch = idx - r * C;
    const int* pc = pcols + (size_t)r * 4;
    float ssum = 0.f;
#pragma unroll
    for (int f = 0; f < 4; ++f) ssum += in[(size_t)pc[f] * C + ch];
    out[(size_t)r * ld + ch] = (f16)(0.25f * ssum);
}

// ---------------- final linear ----------------

__global__ __launch_bounds__(256) void linear10_k(const float* __restrict__ h, const void* __restrict__ lw,
                                                  float* __restrict__ accum, int LIN, const int* __restrict__ flag) {
    int isf = flag[0];
    int c = blockIdx.y;
    int t = threadIdx.x;
    int nvec = LIN >> 3;
    int stride = gridDim.x * 256;
    float p = 0.f;
    const float4* h4 = (const float4*)h;
    if (isf) {
        const float4* lw4 = (const float4*)lw + (size_t)c * (LIN >> 2);
        for (int i = blockIdx.x * 256 + t; i < nvec; i += stride) {
            float4 a0 = h4[2 * i], a1 = h4[2 * i + 1];
            float4 b0 = lw4[2 * i], b1 = lw4[2 * i + 1];
            p += a0.x * b0.x + a0.y * b0.y + a0.z * b0.z + a0.w * b0.w
               + a1.x * b1.x + a1.y * b1.y + a1.z * b1.z + a1.w * b1.w;
        }
    } else {
        const uint4* lwv = (const uint4*)lw + (size_t)c * nvec;
        for (int i = blockIdx.x * 256 + t; i < nvec; i += stride) {
            uint4 w4 = lwv[i];
            float4 a0 = h4[2 * i], a1 = h4[2 * i + 1];
            p += a0.x * blo(w4.x) + a0.y * bhi(w4.x)
               + a0.z * blo(w4.y) + a0.w * bhi(w4.y)
               + a1.x * blo(w4.z) + a1.y * bhi(w4.z)
               + a1.z * blo(w4.w) + a1.w * bhi(w4.w);
        }
    }
    for (int off2 = 32; off2 > 0; off2 >>= 1) p += __shfl_down(p, off2);
    __shared__ float wsum[4];
    int wv = t >> 6, lane = t & 63;
    if (lane == 0) wsum[wv] = p;
    __syncthreads();
    if (t == 0) unsafeAtomicAdd(&accum[c], wsum[0] + wsum[1] + wsum[2] + wsum[3]);
}

__global__ void finalize_k(const float* __restrict__ accum, const void* __restrict__ lb,
                           void* __restrict__ outp, const int* __restrict__ flag) {
    int isf = flag[0];
    int t = threadIdx.x;
    if (t < NCLS) {
        float lbv;
        if (isf) lbv = ((const float*)lb)[t];
        else     lbv = b2f(((const bf16*)lb)[t]);
        float v = accum[t] + lbv;
        if (isf) ((float*)outp)[t] = v;
        else     ((bf16*)outp)[t] = __float2bfloat16(v);
    }
}

__global__ void diag_k(void* __restrict__ outp, float val, const int* __restrict__ flag) {
    int isf = flag[0];
    int t = threadIdx.x;
    if (t < NCLS) {
        if (isf) ((float*)outp)[t] = val;
        else     ((bf16*)outp)[t] = __float2bfloat16(val);
    }
}

// ---------------- orchestration ----------------

extern "C" void kernel_launch(void* const* d_in, const int* in_sizes, int n_in,
                              void* d_out, int out_size, void* d_ws, size_t ws_size,
                              hipStream_t stream) {
    const void* x  = d_in[0];
    const int* ei0 = (const int*)d_in[1];
    const int* ei1 = (const int*)d_in[2];
    const int* ei2 = (const int*)d_in[3];
    const int* pc0 = (const int*)d_in[4];
    const int* pc1 = (const int*)d_in[5];
    const void* w0 = d_in[6];
    const void* b0 = d_in[7];
    const void* w1 = d_in[8];
    const void* b1 = d_in[9];
    const void* w2 = d_in[10];
    const void* b2 = d_in[11];
    const void* lw = d_in[12];
    const void* lb = d_in[13];

    const int E0 = in_sizes[1] / 2, E1 = in_sizes[2] / 2, E2 = in_sizes[3] / 2;

    // ---- workspace layout (~167 MB; ws ~512 MB per harness poison) ----
    char* base = (char*)d_ws;
    size_t off = 0;
    auto alloc = [&](size_t bytes) -> void* {
        void* p = base + off;
        off += (bytes + 255) & ~(size_t)255;
        return p;
    };
    f16*      TxAll = (f16*)alloc((size_t)19200000 * 2);     // max(N0*24, N1*384, N2*768) halves
    float*    OutB  = (float*)alloc((size_t)12800000 * 4);   // max(N0*64, N1*128, N2*256)
    int*      colS  = (int*)alloc((size_t)EMAX * 4);
    unsigned* colB  = (unsigned*)alloc((size_t)NBUK_MAX * CAPB * 4);
    int*      ptr   = (int*)alloc((size_t)(N0 + 1) * 4);
    float*    dinv  = (float*)alloc((size_t)N0 * 4);
    int*      tail  = (int*)alloc((size_t)NBUK_MAX * 4);
    int*      bbase = (int*)alloc((size_t)NBUK_MAX * 4);
    float*    accum = (float*)alloc(64);
    int*      flag  = (int*)(accum + 16);

    detect_k<<<1, 256, 0, stream>>>((const unsigned int*)x, flag);

    const size_t NEED = 168000000;
    if (ws_size < NEED) {
        diag_k<<<1, 64, 0, stream>>>(d_out, (float)(ws_size >> 20), flag);
        return;
    }

    struct Lvl {
        int n, E, cin, cout;
        const int *rows, *cols;
        const void *w, *b;
        int relu;
    };
    Lvl L[3] = {
        {N0, E0, 3, 64, ei0, ei0 + E0, w0, b0, 1},
        {N1, E1, 64, 128, ei1, ei1 + E1, w1, b1, 1},
        {N2, E2, 128, 256, ei2, ei2 + E2, w2, b2, 0},
    };

    for (int li = 0; li < 3; ++li) {
        const Lvl& v = L[li];
        int n = v.n, E = v.E, cin = v.cin, cout = v.cout;
        int pgrid = (n + 3) / 4;
        int nbuk = (n + BROWS - 1) >> SB;
        int ld = (li == 0) ? 24 : KCH * cin;   // L0 packed: slot stride 4
        int slot = (li == 0) ? 4 : cin;

        // hist-free binned CSR build (writes ptr, dinv, colS)
        hipMemsetAsync(tail, 0, (size_t)nbuk * 4, stream);
        {
            size_t shb = (size_t)nbuk * (QCAP + 1) * 4;
            binA_k<<<512, 256, shb, stream>>>(v.rows, v.cols, tail, colB, nbuk, E);
        }
        scanb_k<<<1, 1024, 0, stream>>>(tail, bbase, nbuk, ptr, n);
        binB_k<<<nbuk, 256, 0, stream>>>(tail, bbase, colB, ptr, dinv, colS, n);

        if (li == 0)
            convert_x_k<<<(N0 + 255) / 256, 256, 0, stream>>>(x, TxAll, dinv, N0, flag);

        // Chebyshev recurrence into fused slots
        for (int k = 1; k < KCH; ++k) {
            const f16* hin = TxAll + (size_t)(k - 1) * slot;
            const f16* sub = (k >= 2) ? (TxAll + (size_t)(k - 2) * slot) : nullptr;
            f16* o = TxAll + (size_t)k * slot;
            float alpha = (k >= 2) ? 2.f : 1.f;
            if (li == 0)
                prop_narrow_k<<<pgrid, 256, 0, stream>>>(ptr, colS, dinv, hin, sub, o, n, alpha, k >= 2);
            else if (cin == 64)
                prop_wide2_k<<<pgrid, 256, 0, stream>>>(ptr, colS, dinv, hin, sub, o, ld, n, alpha, k >= 2);
            else
                prop_wide1h_k<<<pgrid, 256, 0, stream>>>(ptr, colS, dinv, hin, sub, o, ld, n, alpha, k >= 2);
        }

        // GEMM: OutB[n,cout] = TxAll @ w + bias (+relu)
        dim3 gg(cout / 64, (n + 63) / 64);
        if (li == 0)
            gemm_k<<<gg, 256, 0, stream>>>(TxAll, ld, v.w, v.b, OutB, n, cout, KCH * cin, 4 | 8 | (v.relu ? 1 : 0), flag);
        else
            gemm_mfma_k<<<gg, 256, 0, stream>>>(TxAll, ld, v.w, v.b, OutB, n, cout, KCH * cin, 4 | (v.relu ? 1 : 0), flag);

        // pool into next level's slot0
        if (li == 0)
            pool_k<<<(N1 * 64 + 255) / 256, 256, 0, stream>>>(OutB, pc0, TxAll, N1, 64, KCH * 64);
        else if (li == 1)
            pool_k<<<(N2 * 128 + 255) / 256, 256, 0, stream>>>(OutB, pc1, TxAll, N2, 128, KCH * 128);
    }

    hipMemsetAsync(accum, 0, 64, stream);
    {
        dim3 lg(128, NCLS);
        linear10_k<<<lg, 256, 0, stream>>>(OutB, lw, accum, N2 * 256, flag);
    }
    finalize_k<<<1, 64, 0, stream>>>(accum, lb, d_out, flag);
}

// Round 9
// 1294.483 us; speedup vs baseline: 2.0671x; 1.0693x over previous
//
#include <hip/hip_runtime.h>
#include <hip/hip_bf16.h>

// ChebNet classifier: 3x ChebConv(K=6) + pool + linear.
// Round 9: CSR build rewritten as deterministic two-pass partition:
//   binH  — per-block LDS histogram of a 12.5k-edge tile -> cntBB[p][b] (coalesced)
//   scanBB— per-bucket scan over the 512 block counts -> within-bucket offsets + totals
//   binS  — re-read tile, bucket-order in LDS, wave-per-bucket coalesced copy-out
// (round 8's binA was serialization-bound: 49 iters x 2 barriers + serial 16-entry
// flushes at 20% occupancy). Also: prop_narrow now 2 rows/wave (mean deg=32 was
// idling half of each 64-lane wave).

#define N0 200000
#define N1 50000
#define N2 12500
#define KCH 6
#define NCLS 10

#define SB 8                 // bucket = 256 rows
#define BROWS 256
#define BCAP 14336           // binB LDS capacity (mean 8192, +68 sigma)
#define NBUK_MAX 800
#define NBLK 512             // partition blocks
#define TILE_MAX 12500       // ceil(6.4M/512)
#define EMAX 6400000

typedef __hip_bfloat16 bf16;
typedef _Float16 f16;
typedef f16 f16x2 __attribute__((ext_vector_type(2)));
typedef f16 f16x4 __attribute__((ext_vector_type(4)));
typedef f16 f16x8 __attribute__((ext_vector_type(8)));
typedef float f32x4 __attribute__((ext_vector_type(4)));

static __device__ __forceinline__ float b2f(bf16 v) { return __bfloat162float(v); }
static __device__ __forceinline__ float blo(unsigned u) { return __uint_as_float(u << 16); }
static __device__ __forceinline__ float bhi(unsigned u) { return __uint_as_float(u & 0xFFFF0000u); }

// ---------------- dtype detection (1 = fp32, 0 = bf16) ----------------
__global__ void detect_k(const unsigned int* __restrict__ xb, int* __restrict__ flag) {
    __shared__ int cs;
    int t = threadIdx.x;
    if (t == 0) cs = 0;
    __syncthreads();
    unsigned w = xb[t];
    unsigned e = (w >> 7) & 0xFFu;
    if (e >= 0x30u && e <= 0x43u) atomicAdd(&cs, 1);
    __syncthreads();
    if (t == 0) flag[0] = (cs < 128) ? 1 : 0;
}

// ---------------- deterministic binned CSR build ----------------

// binH: per-block bucket histogram of its tile.
__global__ __launch_bounds__(256) void binH_k(const int* __restrict__ rows, const int* __restrict__ cols,
                                              int* __restrict__ cntBB, int nbuk, int E, int tile) {
    __shared__ int cnt[NBUK_MAX];
    int t = threadIdx.x;
    for (int i = t; i < nbuk; i += 256) cnt[i] = 0;
    __syncthreads();
    int beg = blockIdx.x * tile;
    int end = beg + tile;
    if (end > E) end = E;
    for (int idx = beg + t; idx < end; idx += 256) {
        int r = rows[idx], c = cols[idx];
        if (r != c) atomicAdd(&cnt[r >> SB], 1);
    }
    __syncthreads();
    for (int i = t; i < nbuk; i += 256) cntBB[(size_t)blockIdx.x * nbuk + i] = cnt[i];
}

// scanBB: per bucket b, exclusive scan over the NBLK block counts; btot[b] = total.
__global__ __launch_bounds__(256) void scanBB_k(int* __restrict__ cntBB, int* __restrict__ btot, int nbuk) {
    __shared__ int ps[256];
    int b = blockIdx.x, t = threadIdx.x;
    int v0 = cntBB[(size_t)(2 * t) * nbuk + b];
    int v1 = cntBB[(size_t)(2 * t + 1) * nbuk + b];
    int pt = v0 + v1;
    ps[t] = pt;
    __syncthreads();
    for (int off = 1; off < 256; off <<= 1) {
        int x = (t >= off) ? ps[t - off] : 0;
        __syncthreads();
        ps[t] += x;
        __syncthreads();
    }
    int ex = ps[t] - pt;
    cntBB[(size_t)(2 * t) * nbuk + b] = ex;
    cntBB[(size_t)(2 * t + 1) * nbuk + b] = ex + v0;
    if (t == 255) btot[b] = ps[255];
}

// scanb: exclusive scan of bucket totals -> bbase; ptr[n] = total edges.
__global__ __launch_bounds__(1024) void scanb_k(const int* __restrict__ btot, int* __restrict__ bbase,
                                                int nbuk, int* __restrict__ ptr, int n) {
    __shared__ int s[1024];
    int t = threadIdx.x;
    int v = (t < nbuk) ? btot[t] : 0;
    s[t] = v;
    __syncthreads();
    for (int off = 1; off < 1024; off <<= 1) {
        int x = (t >= off) ? s[t - off] : 0;
        __syncthreads();
        s[t] += x;
        __syncthreads();
    }
    if (t < nbuk) bbase[t] = s[t] - v;
    if (t == 1023) ptr[n] = s[1023];
}

// binS: scatter tile into bucket-major order in LDS; coalesced copy-out.
__global__ __launch_bounds__(256) void binS_k(const int* __restrict__ rows, const int* __restrict__ cols,
                                              const int* __restrict__ cntBB, const int* __restrict__ bbase,
                                              unsigned* __restrict__ colB, int nbuk, int E, int tile) {
    __shared__ int lcnt[NBUK_MAX];
    __shared__ int lexc[NBUK_MAX];
    __shared__ int lfill[NBUK_MAX];
    __shared__ int gstart[NBUK_MAX];
    __shared__ int ps[256];
    __shared__ unsigned scol[TILE_MAX];
    int t = threadIdx.x;
    for (int i = t; i < nbuk; i += 256) { lcnt[i] = 0; lfill[i] = 0; }
    __syncthreads();
    int beg = blockIdx.x * tile;
    int end = beg + tile;
    if (end > E) end = E;
    // pass 1: count
    for (int idx = beg + t; idx < end; idx += 256) {
        int r = rows[idx], c = cols[idx];
        if (r != c) atomicAdd(&lcnt[r >> SB], 1);
    }
    __syncthreads();
    // scan lcnt -> lexc (4 per thread)
    int idx4 = 4 * t;
    int c4[4];
#pragma unroll
    for (int i = 0; i < 4; ++i) c4[i] = (idx4 + i < nbuk) ? lcnt[idx4 + i] : 0;
    int tot = c4[0] + c4[1] + c4[2] + c4[3];
    ps[t] = tot;
    __syncthreads();
    for (int off = 1; off < 256; off <<= 1) {
        int x = (t >= off) ? ps[t - off] : 0;
        __syncthreads();
        ps[t] += x;
        __syncthreads();
    }
    int run = ps[t] - tot;
#pragma unroll
    for (int i = 0; i < 4; ++i) {
        if (idx4 + i < nbuk) lexc[idx4 + i] = run;
        run += c4[i];
    }
    for (int i = t; i < nbuk; i += 256) gstart[i] = bbase[i] + cntBB[(size_t)blockIdx.x * nbuk + i];
    __syncthreads();
    // pass 2: scatter into LDS bucket-major
    for (int idx = beg + t; idx < end; idx += 256) {
        int r = rows[idx], c = cols[idx];
        if (r != c) {
            int b = r >> SB;
            int s = atomicAdd(&lfill[b], 1);
            scol[lexc[b] + s] = ((unsigned)(r & (BROWS - 1)) << 18) | (unsigned)c;
        }
    }
    __syncthreads();
    // copy-out: wave per bucket, coalesced
    int wv = t >> 6, lane = t & 63;
    for (int b = wv; b < nbuk; b += 4) {
        int cnt2 = lcnt[b];
        int lsrc = lexc[b], gdst = gstart[b];
        for (int i = lane; i < cnt2; i += 64) colB[gdst + i] = scol[lsrc + i];
    }
}

// binB: per bucket — row counts + scan in LDS, write ptr/dinv, row-sort slab, write colS.
__global__ __launch_bounds__(256) void binB_k(const int* __restrict__ btot, const int* __restrict__ bbase,
                                              const unsigned* __restrict__ colB,
                                              int* __restrict__ ptr, float* __restrict__ dinv,
                                              int* __restrict__ colS, int n) {
    __shared__ int lcnt[BROWS];
    __shared__ int lexc[BROWS];
    __shared__ int lfill[BROWS];
    __shared__ int scol[BCAP];
    int b = blockIdx.x;
    int t = threadIdx.x;
    int rowbase = b << SB;
    int rowend = rowbase + BROWS;
    if (rowend > n) rowend = n;
    int nrows = rowend - rowbase;
    int count = btot[b];
    int base = bbase[b];
    const unsigned* slab = colB + base;
    lcnt[t] = 0;
    __syncthreads();
    for (int i = t; i < count; i += 256) atomicAdd(&lcnt[slab[i] >> 18], 1);
    __syncthreads();
    int v = lcnt[t];
    lexc[t] = v;
    __syncthreads();
    for (int off = 1; off < 256; off <<= 1) {
        int x = (t >= off) ? lexc[t - off] : 0;
        __syncthreads();
        lexc[t] += x;
        __syncthreads();
    }
    int excl = lexc[t] - v;
    __syncthreads();
    lexc[t] = excl;
    __syncthreads();
    if (t < nrows) {
        ptr[rowbase + t] = base + excl;
        dinv[rowbase + t] = (v > 0) ? rsqrtf((float)v) : 0.f;
    }
    int nh = (count <= BCAP) ? 1 : 2;    // 2-half path statistically unreachable
    int rspan = BROWS / nh;
    for (int h = 0; h < nh; ++h) {
        int rowLo = h * rspan, rowHi = rowLo + rspan;
        int segOff = lexc[rowLo];
        int segEnd = (rowHi >= BROWS) ? count : lexc[rowHi];
        int segCnt = segEnd - segOff;
        lfill[t] = 0;
        __syncthreads();
        for (int i = t; i < count; i += 256) {
            unsigned pk = slab[i];
            int rl = pk >> 18;
            if (rl >= rowLo && rl < rowHi) {
                int s = atomicAdd(&lfill[rl], 1);
                scol[lexc[rl] + s - segOff] = (int)(pk & 0x3FFFFu);
            }
        }
        __syncthreads();
        for (int i = t; i < segCnt; i += 256) colS[base + segOff + i] = scol[i];
        __syncthreads();
    }
}

// ---------------- feature staging: x -> packed [h0,h1,h2,dinv] (ld=24) ----------------

__global__ __launch_bounds__(256) void convert_x_k(const void* __restrict__ x, f16* __restrict__ Tx,
                                                   const float* __restrict__ dinv, int n,
                                                   const int* __restrict__ flag) {
    int isf = flag[0];
    int r = blockIdx.x * 256 + threadIdx.x;
    if (r >= n) return;
    float v0, v1, v2;
    if (isf) {
        const float* xf = (const float*)x;
        v0 = xf[3 * r]; v1 = xf[3 * r + 1]; v2 = xf[3 * r + 2];
    } else {
        const bf16* xh = (const bf16*)x;
        v0 = b2f(xh[3 * r]); v1 = b2f(xh[3 * r + 1]); v2 = b2f(xh[3 * r + 2]);
    }
    f16x4 pk = {(f16)v0, (f16)v1, (f16)v2, (f16)dinv[r]};
    *(f16x4*)(Tx + (size_t)r * 24) = pk;
}

// ---------------- propagation ----------------

// L0: packed rows, 8B gather/edge; 2 rows per wave (32 lanes each, mean deg 32).
__global__ __launch_bounds__(256) void prop_narrow_k(const int* __restrict__ ptr, const int* __restrict__ colS,
                                                     const float* __restrict__ dinv, const f16* __restrict__ hin,
                                                     const f16* __restrict__ sub, f16* __restrict__ o,
                                                     int n, float alpha, int useSub) {
    int wv = threadIdx.x >> 6, half = (threadIdx.x >> 5) & 1, sl = threadIdx.x & 31;
    int r = blockIdx.x * 8 + wv * 2 + half;
    if (r >= n) return;
    int s = ptr[r], e = ptr[r + 1];
    float dr = dinv[r];
    float a0 = 0.f, a1 = 0.f, a2 = 0.f;
    for (int idx = s + sl; idx < e; idx += 32) {
        int c = colS[idx];
        f16x4 h = *(const f16x4*)(hin + (size_t)c * 24);
        float nrm = -dr * (float)h.w;
        a0 += nrm * (float)h.x;
        a1 += nrm * (float)h.y;
        a2 += nrm * (float)h.z;
    }
#pragma unroll
    for (int off2 = 16; off2 > 0; off2 >>= 1) {
        a0 += __shfl_xor(a0, off2);
        a1 += __shfl_xor(a1, off2);
        a2 += __shfl_xor(a2, off2);
    }
    if (sl == 0) {
        float v0 = alpha * a0, v1 = alpha * a1, v2 = alpha * a2;
        if (useSub) {
            f16x4 sv = *(const f16x4*)(sub + (size_t)r * 24);
            v0 -= (float)sv.x; v1 -= (float)sv.y; v2 -= (float)sv.z;
        }
        f16x4 ov = {(f16)v0, (f16)v1, (f16)v2, (f16)dr};
        *(f16x4*)(o + (size_t)r * 24) = ov;
    }
}

// L1 (cin=64): half-wave p handles edge j+p; lane q covers channel pair 2q.
__global__ __launch_bounds__(256) void prop_wide2_k(const int* __restrict__ ptr, const int* __restrict__ colS,
                                                    const float* __restrict__ dinv, const f16* __restrict__ hin,
                                                    const f16* __restrict__ sub, f16* __restrict__ o,
                                                    int ld, int n, float alpha, int useSub) {
    int wv = threadIdx.x >> 6, lane = threadIdx.x & 63;
    int p = lane >> 5, q = lane & 31;
    int r = blockIdx.x * 4 + wv;
    if (r >= n) return;
    int s = ptr[r], e = ptr[r + 1];
    float dr = dinv[r];
    float ax = 0.f, ay = 0.f;
    for (int base = s; base < e; base += 64) {
        int idx = base + lane;
        int c = 0;
        float dc = 0.f;
        if (idx < e) { c = colS[idx]; dc = dinv[c]; }
        int cnt2 = e - base;
        if (cnt2 > 64) cnt2 = 64;
        int j = 0;
        for (; j + 4 <= cnt2; j += 4) {
            int j0 = j + p, j1 = j + 2 + p;
            int c0 = __shfl(c, j0), c1 = __shfl(c, j1);
            float n0 = -dr * __shfl(dc, j0), n1 = -dr * __shfl(dc, j1);
            f16x2 h0 = *(const f16x2*)(hin + (size_t)c0 * ld + 2 * q);
            f16x2 h1 = *(const f16x2*)(hin + (size_t)c1 * ld + 2 * q);
            ax += n0 * (float)h0.x + n1 * (float)h1.x;
            ay += n0 * (float)h0.y + n1 * (float)h1.y;
        }
        for (; j < cnt2; j += 2) {
            int jj = j + p;
            int valid = jj < cnt2;
            int cc = __shfl(c, valid ? jj : 0);
            float nd = __shfl(dc, valid ? jj : 0);
            float nrm = valid ? -dr * nd : 0.f;
            f16x2 h = *(const f16x2*)(hin + (size_t)cc * ld + 2 * q);
            ax += nrm * (float)h.x;
            ay += nrm * (float)h.y;
        }
    }
    ax += __shfl_xor(ax, 32);
    ay += __shfl_xor(ay, 32);
    if (p == 0) {
        size_t rb = (size_t)r * ld + 2 * q;
        float vx = alpha * ax, vy = alpha * ay;
        if (useSub) {
            f16x2 sv = *(const f16x2*)(sub + rb);
            vx -= (float)sv.x; vy -= (float)sv.y;
        }
        f16x2 ov = {(f16)vx, (f16)vy};
        *(f16x2*)(o + rb) = ov;
    }
}

// L2 (cin=128): lane covers channel pair 2*lane; one edge/step, x4 unroll.
__global__ __launch_bounds__(256) void prop_wide1h_k(const int* __restrict__ ptr, const int* __restrict__ colS,
                                                     const float* __restrict__ dinv, const f16* __restrict__ hin,
                                                     const f16* __restrict__ sub, f16* __restrict__ o,
                                                     int ld, int n, float alpha, int useSub) {
    int wv = threadIdx.x >> 6, lane = threadIdx.x & 63;
    int r = blockIdx.x * 4 + wv;
    if (r >= n) return;
    int s = ptr[r], e = ptr[r + 1];
    float dr = dinv[r];
    float ax = 0.f, ay = 0.f;
    for (int base = s; base < e; base += 64) {
        int idx = base + lane;
        int c = 0;
        float dc = 0.f;
        if (idx < e) { c = colS[idx]; dc = dinv[c]; }
        int cnt2 = e - base;
        if (cnt2 > 64) cnt2 = 64;
        int j = 0;
        for (; j + 4 <= cnt2; j += 4) {
            int c0 = __shfl(c, j), c1 = __shfl(c, j + 1), c2 = __shfl(c, j + 2), c3 = __shfl(c, j + 3);
            float n0 = -dr * __shfl(dc, j), n1 = -dr * __shfl(dc, j + 1);
            float n2 = -dr * __shfl(dc, j + 2), n3 = -dr * __shfl(dc, j + 3);
            f16x2 h0 = *(const f16x2*)(hin + (size_t)c0 * ld + 2 * lane);
            f16x2 h1 = *(const f16x2*)(hin + (size_t)c1 * ld + 2 * lane);
            f16x2 h2 = *(const f16x2*)(hin + (size_t)c2 * ld + 2 * lane);
            f16x2 h3 = *(const f16x2*)(hin + (size_t)c3 * ld + 2 * lane);
            ax += n0 * (float)h0.x + n1 * (float)h1.x + n2 * (float)h2.x + n3 * (float)h3.x;
            ay += n0 * (float)h0.y + n1 * (float)h1.y + n2 * (float)h2.y + n3 * (float)h3.y;
        }
        for (; j < cnt2; ++j) {
            int cc = __shfl(c, j);
            float nrm = -dr * __shfl(dc, j);
            f16x2 h = *(const f16x2*)(hin + (size_t)cc * ld + 2 * lane);
            ax += nrm * (float)h.x;
            ay += nrm * (float)h.y;
        }
    }
    size_t rb = (size_t)r * ld + 2 * lane;
    float vx = alpha * ax, vy = alpha * ay;
    if (useSub) {
        f16x2 sv = *(const f16x2*)(sub + rb);
        vx -= (float)sv.x; vy -= (float)sv.y;
    }
    f16x2 ov = {(f16)vx, (f16)vy};
    *(f16x2*)(o + rb) = ov;
}

// ---------------- MFMA GEMM (L1/L2) ----------------

__global__ __launch_bounds__(256) void gemm_mfma_k(const f16* __restrict__ A, int lda,
                                                   const void* __restrict__ W, const void* __restrict__ bias,
                                                   float* __restrict__ C, int M, int N, int K, int flags,
                                                   const int* __restrict__ flag) {
    __shared__ f16 As[64][40];
    __shared__ f16 Bs[64][40];
    int isf = flag[0];
    int t = threadIdx.x;
    int w = t >> 6, l = t & 63, q = l >> 4, m16 = l & 15;
    int m0 = blockIdx.y * 64, n0 = blockIdx.x * 64;
    f32x4 acc[4] = {};
    for (int k0 = 0; k0 < K; k0 += 32) {
        {
            int row = t >> 2, cg = (t & 3) * 8;
            int gm = m0 + row;
            f16x8 av = {};
            if (gm < M) av = *(const f16x8*)(A + (size_t)gm * lda + k0 + cg);
            *(f16x8*)&As[row][cg] = av;
        }
        {
            int kk = t >> 3, nb = (t & 7) * 8;
            float wv[8];
            if (isf) {
                const float* Wf = (const float*)W + (size_t)(k0 + kk) * N + n0 + nb;
#pragma unroll
                for (int i = 0; i < 8; ++i) wv[i] = Wf[i];
            } else {
                const bf16* Wh = (const bf16*)W + (size_t)(k0 + kk) * N + n0 + nb;
#pragma unroll
                for (int i = 0; i < 8; ++i) wv[i] = b2f(Wh[i]);
            }
#pragma unroll
            for (int i = 0; i < 8; ++i) Bs[nb + i][kk] = (f16)wv[i];
        }
        __syncthreads();
        f16x8 a = *(const f16x8*)&As[w * 16 + m16][q * 8];
        f16x8 b0 = *(const f16x8*)&Bs[m16][q * 8];
        f16x8 b1 = *(const f16x8*)&Bs[16 + m16][q * 8];
        f16x8 b2 = *(const f16x8*)&Bs[32 + m16][q * 8];
        f16x8 b3 = *(const f16x8*)&Bs[48 + m16][q * 8];
        acc[0] = __builtin_amdgcn_mfma_f32_16x16x32_f16(a, b0, acc[0], 0, 0, 0);
        acc[1] = __builtin_amdgcn_mfma_f32_16x16x32_f16(a, b1, acc[1], 0, 0, 0);
        acc[2] = __builtin_amdgcn_mfma_f32_16x16x32_f16(a, b2, acc[2], 0, 0, 0);
        acc[3] = __builtin_amdgcn_mfma_f32_16x16x32_f16(a, b3, acc[3], 0, 0, 0);
        __syncthreads();
    }
#pragma unroll
    for (int tile = 0; tile < 4; ++tile) {
        int gn = n0 + tile * 16 + m16;
        float bv = 0.f;
        if (flags & 4) {
            if (isf) bv = ((const float*)bias)[gn];
            else     bv = b2f(((const bf16*)bias)[gn]);
        }
#pragma unroll
        for (int i = 0; i < 4; ++i) {
            int gm = m0 + w * 16 + q * 4 + i;
            if (gm < M) {
                float v = acc[tile][i] + bv;
                if (flags & 1) v = fmaxf(v, 0.f);
                C[(size_t)gm * N + gn] = v;
            }
        }
    }
}

// ---------------- vector GEMM (L0 only; packed-A: phys = gk + gk/3) ----------------

__global__ __launch_bounds__(256) void gemm_k(const f16* __restrict__ A, int lda,
                                              const void* __restrict__ W,
                                              const void* __restrict__ bias,
                                              float* __restrict__ C, int M, int N, int K, int flags,
                                              const int* __restrict__ flag) {
    __shared__ float As[16][65];
    __shared__ float Ws[16][64];
    int isf = flag[0];
    int pack3 = flags & 8;
    int t = threadIdx.x;
    int tn = t & 15, tm = t >> 4;
    int m0 = blockIdx.y * 64, n0 = blockIdx.x * 64;
    float acc[4][4] = {};
    for (int k0 = 0; k0 < K; k0 += 16) {
#pragma unroll
        for (int i = 0; i < 4; ++i) {
            int idx = i * 256 + t;
            int m = idx >> 4, k = idx & 15;
            int gm = m0 + m, gk = k0 + k;
            int phys = pack3 ? (gk + gk / 3) : gk;
            As[k][m] = (gm < M && gk < K) ? (float)A[(size_t)gm * lda + phys] : 0.f;
        }
        if (isf) {
            const float* Wf = (const float*)W;
#pragma unroll
            for (int i = 0; i < 4; ++i) {
                int idx = i * 256 + t;
                int k = idx >> 6, nn = idx & 63;
                int gk = k0 + k;
                Ws[k][nn] = (gk < K) ? Wf[(size_t)gk * N + n0 + nn] : 0.f;
            }
        } else {
            const bf16* Wh = (const bf16*)W;
#pragma unroll
            for (int i = 0; i < 4; ++i) {
                int idx = i * 256 + t;
                int k = idx >> 6, nn = idx & 63;
                int gk = k0 + k;
                Ws[k][nn] = (gk < K) ? b2f(Wh[(size_t)gk * N + n0 + nn]) : 0.f;
            }
        }
        __syncthreads();
#pragma unroll
        for (int kk = 0; kk < 16; ++kk) {
            float a[4], b[4];
#pragma unroll
            for (int i = 0; i < 4; ++i) a[i] = As[kk][tm * 4 + i];
#pragma unroll
            for (int j = 0; j < 4; ++j) b[j] = Ws[kk][tn * 4 + j];
#pragma unroll
            for (int i = 0; i < 4; ++i)
#pragma unroll
                for (int j = 0; j < 4; ++j) acc[i][j] += a[i] * b[j];
        }
        __syncthreads();
    }
#pragma unroll
    for (int i = 0; i < 4; ++i) {
        int gm = m0 + tm * 4 + i;
        if (gm >= M) continue;
#pragma unroll
        for (int j = 0; j < 4; ++j) {
            int gn = n0 + tn * 4 + j;
            size_t ci = (size_t)gm * N + gn;
            float v = acc[i][j];
            if (flags & 4) {
                if (isf) v += ((const float*)bias)[gn];
                else     v += b2f(((const bf16*)bias)[gn]);
            }
            if (flags & 1) v = fmaxf(v, 0.f);
            C[ci] = v;
        }
    }
}

// ---------------- pooling ----------------

__global__ __launch_bounds__(256) void pool_k(const float* __restrict__ in, const int* __restrict__ pcols,
                                              f16* __restrict__ out, int n_out, int C, int ld) {
    int idx = blockIdx.x * 256 + threadIdx.x;
    if (idx >= n_out * C) return;
    int r = idx / C, ch = idx - r * C;
    const int* pc = pcols + (size_t)r * 4;
    float ssum = 0.f;
#pragma unroll
    for (int f = 0; f < 4; ++f) ssum += in[(size_t)pc[f] * C + ch];
    out[(size_t)r * ld + ch] = (f16)(0.25f * ssum);
}

// ---------------- final linear ----------------

__global__ __launch_bounds__(256) void linear10_k(const float* __restrict__ h, const void* __restrict__ lw,
                                                  float* __restrict__ accum, int LIN, const int* __restrict__ flag) {
    int isf = flag[0];
    int c = blockIdx.y;
    int t = threadIdx.x;
    int nvec = LIN >> 3;
    int stride = gridDim.x * 256;
    float p = 0.f;
    const float4* h4 = (const float4*)h;
    if (isf) {
        const float4* lw4 = (const float4*)lw + (size_t)c * (LIN >> 2);
        for (int i = blockIdx.x * 256 + t; i < nvec; i += stride) {
            float4 a0 = h4[2 * i], a1 = h4[2 * i + 1];
            float4 b0 = lw4[2 * i], b1 = lw4[2 * i + 1];
            p += a0.x * b0.x + a0.y * b0.y + a0.z * b0.z + a0.w * b0.w
               + a1.x * b1.x + a1.y * b1.y + a1.z * b1.z + a1.w * b1.w;
        }
    } else {
        const uint4* lwv = (const uint4*)lw + (size_t)c * nvec;
        for (int i = blockIdx.x * 256 + t; i < nvec; i += stride) {
            uint4 w4 = lwv[i];
            float4 a0 = h4[2 * i], a1 = h4[2 * i + 1];
            p += a0.x * blo(w4.x) + a0.y * bhi(w4.x)
               + a0.z * blo(w4.y) + a0.w * bhi(w4.y)
               + a1.x * blo(w4.z) + a1.y * bhi(w4.z)
               + a1.z * blo(w4.w) + a1.w * bhi(w4.w);
        }
    }
    for (int off2 = 32; off2 > 0; off2 >>= 1) p += __shfl_down(p, off2);
    __shared__ float wsum[4];
    int wv = t >> 6, lane = t & 63;
    if (lane == 0) wsum[wv] = p;
    __syncthreads();
    if (t == 0) unsafeAtomicAdd(&accum[c], wsum[0] + wsum[1] + wsum[2] + wsum[3]);
}

__global__ void finalize_k(const float* __restrict__ accum, const void* __restrict__ lb,
                           void* __restrict__ outp, const int* __restrict__ flag) {
    int isf = flag[0];
    int t = threadIdx.x;
    if (t < NCLS) {
        float lbv;
        if (isf) lbv = ((const float*)lb)[t];
        else     lbv = b2f(((const bf16*)lb)[t]);
        float v = accum[t] + lbv;
        if (isf) ((float*)outp)[t] = v;
        else     ((bf16*)outp)[t] = __float2bfloat16(v);
    }
}

__global__ void diag_k(void* __restrict__ outp, float val, const int* __restrict__ flag) {
    int isf = flag[0];
    int t = threadIdx.x;
    if (t < NCLS) {
        if (isf) ((float*)outp)[t] = val;
        else     ((bf16*)outp)[t] = __float2bfloat16(val);
    }
}

// ---------------- orchestration ----------------

extern "C" void kernel_launch(void* const* d_in, const int* in_sizes, int n_in,
                              void* d_out, int out_size, void* d_ws, size_t ws_size,
                              hipStream_t stream) {
    const void* x  = d_in[0];
    const int* ei0 = (const int*)d_in[1];
    const int* ei1 = (const int*)d_in[2];
    const int* ei2 = (const int*)d_in[3];
    const int* pc0 = (const int*)d_in[4];
    const int* pc1 = (const int*)d_in[5];
    const void* w0 = d_in[6];
    const void* b0 = d_in[7];
    const void* w1 = d_in[8];
    const void* b1 = d_in[9];
    const void* w2 = d_in[10];
    const void* b2 = d_in[11];
    const void* lw = d_in[12];
    const void* lb = d_in[13];

    const int E0 = in_sizes[1] / 2, E1 = in_sizes[2] / 2, E2 = in_sizes[3] / 2;

    // ---- workspace layout (~145 MB; ws ~512 MB per harness poison) ----
    char* base = (char*)d_ws;
    size_t off = 0;
    auto alloc = [&](size_t bytes) -> void* {
        void* p = base + off;
        off += (bytes + 255) & ~(size_t)255;
        return p;
    };
    f16*      TxAll = (f16*)alloc((size_t)19200000 * 2);
    float*    OutB  = (float*)alloc((size_t)12800000 * 4);
    int*      colS  = (int*)alloc((size_t)EMAX * 4);
    unsigned* colB  = (unsigned*)alloc((size_t)EMAX * 4);
    int*      cntBB = (int*)alloc((size_t)NBLK * NBUK_MAX * 4);
    int*      ptr   = (int*)alloc((size_t)(N0 + 1) * 4);
    float*    dinv  = (float*)alloc((size_t)N0 * 4);
    int*      btot  = (int*)alloc((size_t)NBUK_MAX * 4);
    int*      bbase = (int*)alloc((size_t)NBUK_MAX * 4);
    float*    accum = (float*)alloc(64);
    int*      flag  = (int*)(accum + 16);

    detect_k<<<1, 256, 0, stream>>>((const unsigned int*)x, flag);

    const size_t NEED = 150000000;
    if (ws_size < NEED) {
        diag_k<<<1, 64, 0, stream>>>(d_out, (float)(ws_size >> 20), flag);
        return;
    }

    struct Lvl {
        int n, E, cin, cout;
        const int *rows, *cols;
        const void *w, *b;
        int relu;
    };
    Lvl L[3] = {
        {N0, E0, 3, 64, ei0, ei0 + E0, w0, b0, 1},
        {N1, E1, 64, 128, ei1, ei1 + E1, w1, b1, 1},
        {N2, E2, 128, 256, ei2, ei2 + E2, w2, b2, 0},
    };

    for (int li = 0; li < 3; ++li) {
        const Lvl& v = L[li];
        int n = v.n, E = v.E, cin = v.cin, cout = v.cout;
        int nbuk = (n + BROWS - 1) >> SB;
        int tile = (E + NBLK - 1) / NBLK;
        int ld = (li == 0) ? 24 : KCH * cin;   // L0 packed: slot stride 4
        int slot = (li == 0) ? 4 : cin;

        // deterministic binned CSR build (writes ptr, dinv, colS)
        binH_k<<<NBLK, 256, 0, stream>>>(v.rows, v.cols, cntBB, nbuk, E, tile);
        scanBB_k<<<nbuk, 256, 0, stream>>>(cntBB, btot, nbuk);
        scanb_k<<<1, 1024, 0, stream>>>(btot, bbase, nbuk, ptr, n);
        binS_k<<<NBLK, 256, 0, stream>>>(v.rows, v.cols, cntBB, bbase, colB, nbuk, E, tile);
        binB_k<<<nbuk, 256, 0, stream>>>(btot, bbase, colB, ptr, dinv, colS, n);

        if (li == 0)
            convert_x_k<<<(N0 + 255) / 256, 256, 0, stream>>>(x, TxAll, dinv, N0, flag);

        // Chebyshev recurrence into fused slots
        for (int k = 1; k < KCH; ++k) {
            const f16* hin = TxAll + (size_t)(k - 1) * slot;
            const f16* sub = (k >= 2) ? (TxAll + (size_t)(k - 2) * slot) : nullptr;
            f16* o = TxAll + (size_t)k * slot;
            float alpha = (k >= 2) ? 2.f : 1.f;
            if (li == 0)
                prop_narrow_k<<<(n + 7) / 8, 256, 0, stream>>>(ptr, colS, dinv, hin, sub, o, n, alpha, k >= 2);
            else if (cin == 64)
                prop_wide2_k<<<(n + 3) / 4, 256, 0, stream>>>(ptr, colS, dinv, hin, sub, o, ld, n, alpha, k >= 2);
            else
                prop_wide1h_k<<<(n + 3) / 4, 256, 0, stream>>>(ptr, colS, dinv, hin, sub, o, ld, n, alpha, k >= 2);
        }

        // GEMM: OutB[n,cout] = TxAll @ w + bias (+relu)
        dim3 gg(cout / 64, (n + 63) / 64);
        if (li == 0)
            gemm_k<<<gg, 256, 0, stream>>>(TxAll, ld, v.w, v.b, OutB, n, cout, KCH * cin, 4 | 8 | (v.relu ? 1 : 0), flag);
        else
            gemm_mfma_k<<<gg, 256, 0, stream>>>(TxAll, ld, v.w, v.b, OutB, n, cout, KCH * cin, 4 | (v.relu ? 1 : 0), flag);

        // pool into next level's slot0
        if (li == 0)
            pool_k<<<(N1 * 64 + 255) / 256, 256, 0, stream>>>(OutB, pc0, TxAll, N1, 64, KCH * 64);
        else if (li == 1)
            pool_k<<<(N2 * 128 + 255) / 256, 256, 0, stream>>>(OutB, pc1, TxAll, N2, 128, KCH * 128);
    }

    hipMemsetAsync(accum, 0, 64, stream);
    {
        dim3 lg(128, NCLS);
        linear10_k<<<lg, 256, 0, stream>>>(OutB, lw, accum, N2 * 256, flag);
    }
    finalize_k<<<1, 64, 0, stream>>>(accum, lb, d_out, flag);
}

// Round 10
// 1094.377 us; speedup vs baseline: 2.4450x; 1.1828x over previous
//
#include <hip/hip_runtime.h>
#include <hip/hip_bf16.h>

// ChebNet classifier: 3x ChebConv(K=6) + pool + linear.
// Round 10: (1) L0 prop gathers from DENSE ping-pong f16x4 buffers (1.6 MB,
// fits per-XCD L2). Round 9's 48B-strided gather source spread the working
// set to 9.6MB -> L2 thrash -> 260MB memory-side fetch per prop (5x78us).
// Props write both the dense buffer (next gather src) and the TxAll slot
// (GEMM A). (2) binS: NBLK 512->1024, scol 25KB -> ~39KB LDS -> 4 blocks/CU
// (was 20.7% occupancy). (3) binB: BCAP 10240 -> 3 blocks/CU.

#define N0 200000
#define N1 50000
#define N2 12500
#define KCH 6
#define NCLS 10

#define SB 8                 // bucket = 256 rows
#define BROWS 256
#define BCAP 10240           // binB LDS capacity (mean 8109, +23 sigma; 2-half fallback)
#define NBUK_MAX 800
#define NBLK 1024            // partition blocks
#define TILE_MAX 6250        // ceil(6.4M/1024)
#define EMAX 6400000

typedef __hip_bfloat16 bf16;
typedef _Float16 f16;
typedef f16 f16x2 __attribute__((ext_vector_type(2)));
typedef f16 f16x4 __attribute__((ext_vector_type(4)));
typedef f16 f16x8 __attribute__((ext_vector_type(8)));
typedef float f32x4 __attribute__((ext_vector_type(4)));

static __device__ __forceinline__ float b2f(bf16 v) { return __bfloat162float(v); }
static __device__ __forceinline__ float blo(unsigned u) { return __uint_as_float(u << 16); }
static __device__ __forceinline__ float bhi(unsigned u) { return __uint_as_float(u & 0xFFFF0000u); }

// ---------------- dtype detection (1 = fp32, 0 = bf16) ----------------
__global__ void detect_k(const unsigned int* __restrict__ xb, int* __restrict__ flag) {
    __shared__ int cs;
    int t = threadIdx.x;
    if (t == 0) cs = 0;
    __syncthreads();
    unsigned w = xb[t];
    unsigned e = (w >> 7) & 0xFFu;
    if (e >= 0x30u && e <= 0x43u) atomicAdd(&cs, 1);
    __syncthreads();
    if (t == 0) flag[0] = (cs < 128) ? 1 : 0;
}

// ---------------- deterministic binned CSR build ----------------

__global__ __launch_bounds__(256) void binH_k(const int* __restrict__ rows, const int* __restrict__ cols,
                                              int* __restrict__ cntBB, int nbuk, int E, int tile) {
    __shared__ int cnt[NBUK_MAX];
    int t = threadIdx.x;
    for (int i = t; i < nbuk; i += 256) cnt[i] = 0;
    __syncthreads();
    int beg = blockIdx.x * tile;
    int end = beg + tile;
    if (end > E) end = E;
    for (int idx = beg + t; idx < end; idx += 256) {
        int r = rows[idx], c = cols[idx];
        if (r != c) atomicAdd(&cnt[r >> SB], 1);
    }
    __syncthreads();
    for (int i = t; i < nbuk; i += 256) cntBB[(size_t)blockIdx.x * nbuk + i] = cnt[i];
}

// scanBB: per bucket b, exclusive scan over the NBLK block counts (4/thread).
__global__ __launch_bounds__(256) void scanBB_k(int* __restrict__ cntBB, int* __restrict__ btot, int nbuk) {
    __shared__ int ps[256];
    int b = blockIdx.x, t = threadIdx.x;
    int vals[4];
    int pt = 0;
#pragma unroll
    for (int i = 0; i < 4; ++i) { vals[i] = cntBB[(size_t)(4 * t + i) * nbuk + b]; pt += vals[i]; }
    ps[t] = pt;
    __syncthreads();
    for (int off = 1; off < 256; off <<= 1) {
        int x = (t >= off) ? ps[t - off] : 0;
        __syncthreads();
        ps[t] += x;
        __syncthreads();
    }
    int ex = ps[t] - pt;
#pragma unroll
    for (int i = 0; i < 4; ++i) { cntBB[(size_t)(4 * t + i) * nbuk + b] = ex; ex += vals[i]; }
    if (t == 255) btot[b] = ps[255];
}

__global__ __launch_bounds__(1024) void scanb_k(const int* __restrict__ btot, int* __restrict__ bbase,
                                                int nbuk, int* __restrict__ ptr, int n) {
    __shared__ int s[1024];
    int t = threadIdx.x;
    int v = (t < nbuk) ? btot[t] : 0;
    s[t] = v;
    __syncthreads();
    for (int off = 1; off < 1024; off <<= 1) {
        int x = (t >= off) ? s[t - off] : 0;
        __syncthreads();
        s[t] += x;
        __syncthreads();
    }
    if (t < nbuk) bbase[t] = s[t] - v;
    if (t == 1023) ptr[n] = s[1023];
}

__global__ __launch_bounds__(256) void binS_k(const int* __restrict__ rows, const int* __restrict__ cols,
                                              const int* __restrict__ cntBB, const int* __restrict__ bbase,
                                              unsigned* __restrict__ colB, int nbuk, int E, int tile) {
    __shared__ int lcnt[NBUK_MAX];
    __shared__ int lexc[NBUK_MAX];
    __shared__ int lfill[NBUK_MAX];
    __shared__ int gstart[NBUK_MAX];
    __shared__ int ps[256];
    __shared__ unsigned scol[TILE_MAX];
    int t = threadIdx.x;
    for (int i = t; i < nbuk; i += 256) { lcnt[i] = 0; lfill[i] = 0; }
    __syncthreads();
    int beg = blockIdx.x * tile;
    int end = beg + tile;
    if (end > E) end = E;
    for (int idx = beg + t; idx < end; idx += 256) {
        int r = rows[idx], c = cols[idx];
        if (r != c) atomicAdd(&lcnt[r >> SB], 1);
    }
    __syncthreads();
    int idx4 = 4 * t;
    int c4[4];
#pragma unroll
    for (int i = 0; i < 4; ++i) c4[i] = (idx4 + i < nbuk) ? lcnt[idx4 + i] : 0;
    int tot = c4[0] + c4[1] + c4[2] + c4[3];
    ps[t] = tot;
    __syncthreads();
    for (int off = 1; off < 256; off <<= 1) {
        int x = (t >= off) ? ps[t - off] : 0;
        __syncthreads();
        ps[t] += x;
        __syncthreads();
    }
    int run = ps[t] - tot;
#pragma unroll
    for (int i = 0; i < 4; ++i) {
        if (idx4 + i < nbuk) lexc[idx4 + i] = run;
        run += c4[i];
    }
    for (int i = t; i < nbuk; i += 256) gstart[i] = bbase[i] + cntBB[(size_t)blockIdx.x * nbuk + i];
    __syncthreads();
    for (int idx = beg + t; idx < end; idx += 256) {
        int r = rows[idx], c = cols[idx];
        if (r != c) {
            int b = r >> SB;
            int s = atomicAdd(&lfill[b], 1);
            scol[lexc[b] + s] = ((unsigned)(r & (BROWS - 1)) << 18) | (unsigned)c;
        }
    }
    __syncthreads();
    int wv = t >> 6, lane = t & 63;
    for (int b = wv; b < nbuk; b += 4) {
        int cnt2 = lcnt[b];
        int lsrc = lexc[b], gdst = gstart[b];
        for (int i = lane; i < cnt2; i += 64) colB[gdst + i] = scol[lsrc + i];
    }
}

__global__ __launch_bounds__(256) void binB_k(const int* __restrict__ btot, const int* __restrict__ bbase,
                                              const unsigned* __restrict__ colB,
                                              int* __restrict__ ptr, float* __restrict__ dinv,
                                              int* __restrict__ colS, int n) {
    __shared__ int lcnt[BROWS];
    __shared__ int lexc[BROWS];
    __shared__ int lfill[BROWS];
    __shared__ int scol[BCAP];
    int b = blockIdx.x;
    int t = threadIdx.x;
    int rowbase = b << SB;
    int rowend = rowbase + BROWS;
    if (rowend > n) rowend = n;
    int nrows = rowend - rowbase;
    int count = btot[b];
    int base = bbase[b];
    const unsigned* slab = colB + base;
    lcnt[t] = 0;
    __syncthreads();
    for (int i = t; i < count; i += 256) atomicAdd(&lcnt[slab[i] >> 18], 1);
    __syncthreads();
    int v = lcnt[t];
    lexc[t] = v;
    __syncthreads();
    for (int off = 1; off < 256; off <<= 1) {
        int x = (t >= off) ? lexc[t - off] : 0;
        __syncthreads();
        lexc[t] += x;
        __syncthreads();
    }
    int excl = lexc[t] - v;
    __syncthreads();
    lexc[t] = excl;
    __syncthreads();
    if (t < nrows) {
        ptr[rowbase + t] = base + excl;
        dinv[rowbase + t] = (v > 0) ? rsqrtf((float)v) : 0.f;
    }
    int nh = (count <= BCAP) ? 1 : 2;    // 2-half path statistically unreachable
    int rspan = BROWS / nh;
    for (int h = 0; h < nh; ++h) {
        int rowLo = h * rspan, rowHi = rowLo + rspan;
        int segOff = lexc[rowLo];
        int segEnd = (rowHi >= BROWS) ? count : lexc[rowHi];
        int segCnt = segEnd - segOff;
        lfill[t] = 0;
        __syncthreads();
        for (int i = t; i < count; i += 256) {
            unsigned pk = slab[i];
            int rl = pk >> 18;
            if (rl >= rowLo && rl < rowHi) {
                int s = atomicAdd(&lfill[rl], 1);
                scol[lexc[rl] + s - segOff] = (int)(pk & 0x3FFFFu);
            }
        }
        __syncthreads();
        for (int i = t; i < segCnt; i += 256) colS[base + segOff + i] = scol[i];
        __syncthreads();
    }
}

// ---------------- feature staging: x -> dense G0 + TxAll slot0 ----------------

__global__ __launch_bounds__(256) void convert_x_k(const void* __restrict__ x, f16* __restrict__ Tx,
                                                   f16x4* __restrict__ G0,
                                                   const float* __restrict__ dinv, int n,
                                                   const int* __restrict__ flag) {
    int isf = flag[0];
    int r = blockIdx.x * 256 + threadIdx.x;
    if (r >= n) return;
    float v0, v1, v2;
    if (isf) {
        const float* xf = (const float*)x;
        v0 = xf[3 * r]; v1 = xf[3 * r + 1]; v2 = xf[3 * r + 2];
    } else {
        const bf16* xh = (const bf16*)x;
        v0 = b2f(xh[3 * r]); v1 = b2f(xh[3 * r + 1]); v2 = b2f(xh[3 * r + 2]);
    }
    f16x4 pk = {(f16)v0, (f16)v1, (f16)v2, (f16)dinv[r]};
    *(f16x4*)(Tx + (size_t)r * 24) = pk;
    G0[r] = pk;
}

// ---------------- propagation ----------------

// L0: dense 8B gather (1.6MB source, L2-resident); 2 rows/wave; writes dense
// ping-pong buffer + TxAll slot. sub read is row-local from gout (safe overwrite).
__global__ __launch_bounds__(256) void prop_narrow_k(const int* __restrict__ ptr, const int* __restrict__ colS,
                                                     const float* __restrict__ dinv,
                                                     const f16x4* __restrict__ gin, f16x4* __restrict__ gout,
                                                     f16* __restrict__ oslot,
                                                     int n, float alpha, int useSub) {
    int wv = threadIdx.x >> 6, half = (threadIdx.x >> 5) & 1, sl = threadIdx.x & 31;
    int r = blockIdx.x * 8 + wv * 2 + half;
    if (r >= n) return;
    int s = ptr[r], e = ptr[r + 1];
    float dr = dinv[r];
    float a0 = 0.f, a1 = 0.f, a2 = 0.f;
    for (int idx = s + sl; idx < e; idx += 32) {
        int c = colS[idx];
        f16x4 h = gin[c];
        float nrm = -dr * (float)h.w;
        a0 += nrm * (float)h.x;
        a1 += nrm * (float)h.y;
        a2 += nrm * (float)h.z;
    }
#pragma unroll
    for (int off2 = 16; off2 > 0; off2 >>= 1) {
        a0 += __shfl_xor(a0, off2);
        a1 += __shfl_xor(a1, off2);
        a2 += __shfl_xor(a2, off2);
    }
    if (sl == 0) {
        float v0 = alpha * a0, v1 = alpha * a1, v2 = alpha * a2;
        if (useSub) {
            f16x4 sv = gout[r];
            v0 -= (float)sv.x; v1 -= (float)sv.y; v2 -= (float)sv.z;
        }
        f16x4 ov = {(f16)v0, (f16)v1, (f16)v2, (f16)dr};
        gout[r] = ov;
        *(f16x4*)(oslot + (size_t)r * 24) = ov;
    }
}

// L1 (cin=64): half-wave p handles edge j+p; lane q covers channel pair 2q.
__global__ __launch_bounds__(256) void prop_wide2_k(const int* __restrict__ ptr, const int* __restrict__ colS,
                                                    const float* __restrict__ dinv, const f16* __restrict__ hin,
                                                    const f16* __restrict__ sub, f16* __restrict__ o,
                                                    int ld, int n, float alpha, int useSub) {
    int wv = threadIdx.x >> 6, lane = threadIdx.x & 63;
    int p = lane >> 5, q = lane & 31;
    int r = blockIdx.x * 4 + wv;
    if (r >= n) return;
    int s = ptr[r], e = ptr[r + 1];
    float dr = dinv[r];
    float ax = 0.f, ay = 0.f;
    for (int base = s; base < e; base += 64) {
        int idx = base + lane;
        int c = 0;
        float dc = 0.f;
        if (idx < e) { c = colS[idx]; dc = dinv[c]; }
        int cnt2 = e - base;
        if (cnt2 > 64) cnt2 = 64;
        int j = 0;
        for (; j + 4 <= cnt2; j += 4) {
            int j0 = j + p, j1 = j + 2 + p;
            int c0 = __shfl(c, j0), c1 = __shfl(c, j1);
            float n0 = -dr * __shfl(dc, j0), n1 = -dr * __shfl(dc, j1);
            f16x2 h0 = *(const f16x2*)(hin + (size_t)c0 * ld + 2 * q);
            f16x2 h1 = *(const f16x2*)(hin + (size_t)c1 * ld + 2 * q);
            ax += n0 * (float)h0.x + n1 * (float)h1.x;
            ay += n0 * (float)h0.y + n1 * (float)h1.y;
        }
        for (; j < cnt2; j += 2) {
            int jj = j + p;
            int valid = jj < cnt2;
            int cc = __shfl(c, valid ? jj : 0);
            float nd = __shfl(dc, valid ? jj : 0);
            float nrm = valid ? -dr * nd : 0.f;
            f16x2 h = *(const f16x2*)(hin + (size_t)cc * ld + 2 * q);
            ax += nrm * (float)h.x;
            ay += nrm * (float)h.y;
        }
    }
    ax += __shfl_xor(ax, 32);
    ay += __shfl_xor(ay, 32);
    if (p == 0) {
        size_t rb = (size_t)r * ld + 2 * q;
        float vx = alpha * ax, vy = alpha * ay;
        if (useSub) {
            f16x2 sv = *(const f16x2*)(sub + rb);
            vx -= (float)sv.x; vy -= (float)sv.y;
        }
        f16x2 ov = {(f16)vx, (f16)vy};
        *(f16x2*)(o + rb) = ov;
    }
}

// L2 (cin=128): lane covers channel pair 2*lane; one edge/step, x4 unroll.
__global__ __launch_bounds__(256) void prop_wide1h_k(const int* __restrict__ ptr, const int* __restrict__ colS,
                                                     const float* __restrict__ dinv, const f16* __restrict__ hin,
                                                     const f16* __restrict__ sub, f16* __restrict__ o,
                                                     int ld, int n, float alpha, int useSub) {
    int wv = threadIdx.x >> 6, lane = threadIdx.x & 63;
    int r = blockIdx.x * 4 + wv;
    if (r >= n) return;
    int s = ptr[r], e = ptr[r + 1];
    float dr = dinv[r];
    float ax = 0.f, ay = 0.f;
    for (int base = s; base < e; base += 64) {
        int idx = base + lane;
        int c = 0;
        float dc = 0.f;
        if (idx < e) { c = colS[idx]; dc = dinv[c]; }
        int cnt2 = e - base;
        if (cnt2 > 64) cnt2 = 64;
        int j = 0;
        for (; j + 4 <= cnt2; j += 4) {
            int c0 = __shfl(c, j), c1 = __shfl(c, j + 1), c2 = __shfl(c, j + 2), c3 = __shfl(c, j + 3);
            float n0 = -dr * __shfl(dc, j), n1 = -dr * __shfl(dc, j + 1);
            float n2 = -dr * __shfl(dc, j + 2), n3 = -dr * __shfl(dc, j + 3);
            f16x2 h0 = *(const f16x2*)(hin + (size_t)c0 * ld + 2 * lane);
            f16x2 h1 = *(const f16x2*)(hin + (size_t)c1 * ld + 2 * lane);
            f16x2 h2 = *(const f16x2*)(hin + (size_t)c2 * ld + 2 * lane);
            f16x2 h3 = *(const f16x2*)(hin + (size_t)c3 * ld + 2 * lane);
            ax += n0 * (float)h0.x + n1 * (float)h1.x + n2 * (float)h2.x + n3 * (float)h3.x;
            ay += n0 * (float)h0.y + n1 * (float)h1.y + n2 * (float)h2.y + n3 * (float)h3.y;
        }
        for (; j < cnt2; ++j) {
            int cc = __shfl(c, j);
            float nrm = -dr * __shfl(dc, j);
            f16x2 h = *(const f16x2*)(hin + (size_t)cc * ld + 2 * lane);
            ax += nrm * (float)h.x;
            ay += nrm * (float)h.y;
        }
    }
    size_t rb = (size_t)r * ld + 2 * lane;
    float vx = alpha * ax, vy = alpha * ay;
    if (useSub) {
        f16x2 sv = *(const f16x2*)(sub + rb);
        vx -= (float)sv.x; vy -= (float)sv.y;
    }
    f16x2 ov = {(f16)vx, (f16)vy};
    *(f16x2*)(o + rb) = ov;
}

// ---------------- MFMA GEMM (L1/L2) ----------------

__global__ __launch_bounds__(256) void gemm_mfma_k(const f16* __restrict__ A, int lda,
                                                   const void* __restrict__ W, const void* __restrict__ bias,
                                                   float* __restrict__ C, int M, int N, int K, int flags,
                                                   const int* __restrict__ flag) {
    __shared__ f16 As[64][40];
    __shared__ f16 Bs[64][40];
    int isf = flag[0];
    int t = threadIdx.x;
    int w = t >> 6, l = t & 63, q = l >> 4, m16 = l & 15;
    int m0 = blockIdx.y * 64, n0 = blockIdx.x * 64;
    f32x4 acc[4] = {};
    for (int k0 = 0; k0 < K; k0 += 32) {
        {
            int row = t >> 2, cg = (t & 3) * 8;
            int gm = m0 + row;
            f16x8 av = {};
            if (gm < M) av = *(const f16x8*)(A + (size_t)gm * lda + k0 + cg);
            *(f16x8*)&As[row][cg] = av;
        }
        {
            int kk = t >> 3, nb = (t & 7) * 8;
            float wv[8];
            if (isf) {
                const float* Wf = (const float*)W + (size_t)(k0 + kk) * N + n0 + nb;
#pragma unroll
                for (int i = 0; i < 8; ++i) wv[i] = Wf[i];
            } else {
                const bf16* Wh = (const bf16*)W + (size_t)(k0 + kk) * N + n0 + nb;
#pragma unroll
                for (int i = 0; i < 8; ++i) wv[i] = b2f(Wh[i]);
            }
#pragma unroll
            for (int i = 0; i < 8; ++i) Bs[nb + i][kk] = (f16)wv[i];
        }
        __syncthreads();
        f16x8 a = *(const f16x8*)&As[w * 16 + m16][q * 8];
        f16x8 b0 = *(const f16x8*)&Bs[m16][q * 8];
        f16x8 b1 = *(const f16x8*)&Bs[16 + m16][q * 8];
        f16x8 b2 = *(const f16x8*)&Bs[32 + m16][q * 8];
        f16x8 b3 = *(const f16x8*)&Bs[48 + m16][q * 8];
        acc[0] = __builtin_amdgcn_mfma_f32_16x16x32_f16(a, b0, acc[0], 0, 0, 0);
        acc[1] = __builtin_amdgcn_mfma_f32_16x16x32_f16(a, b1, acc[1], 0, 0, 0);
        acc[2] = __builtin_amdgcn_mfma_f32_16x16x32_f16(a, b2, acc[2], 0, 0, 0);
        acc[3] = __builtin_amdgcn_mfma_f32_16x16x32_f16(a, b3, acc[3], 0, 0, 0);
        __syncthreads();
    }
#pragma unroll
    for (int tile = 0; tile < 4; ++tile) {
        int gn = n0 + tile * 16 + m16;
        float bv = 0.f;
        if (flags & 4) {
            if (isf) bv = ((const float*)bias)[gn];
            else     bv = b2f(((const bf16*)bias)[gn]);
        }
#pragma unroll
        for (int i = 0; i < 4; ++i) {
            int gm = m0 + w * 16 + q * 4 + i;
            if (gm < M) {
                float v = acc[tile][i] + bv;
                if (flags & 1) v = fmaxf(v, 0.f);
                C[(size_t)gm * N + gn] = v;
            }
        }
    }
}

// ---------------- vector GEMM (L0 only; packed-A: phys = gk + gk/3) ----------------

__global__ __launch_bounds__(256) void gemm_k(const f16* __restrict__ A, int lda,
                                              const void* __restrict__ W,
                                              const void* __restrict__ bias,
                                              float* __restrict__ C, int M, int N, int K, int flags,
                                              const int* __restrict__ flag) {
    __shared__ float As[16][65];
    __shared__ float Ws[16][64];
    int isf = flag[0];
    int pack3 = flags & 8;
    int t = threadIdx.x;
    int tn = t & 15, tm = t >> 4;
    int m0 = blockIdx.y * 64, n0 = blockIdx.x * 64;
    float acc[4][4] = {};
    for (int k0 = 0; k0 < K; k0 += 16) {
#pragma unroll
        for (int i = 0; i < 4; ++i) {
            int idx = i * 256 + t;
            int m = idx >> 4, k = idx & 15;
            int gm = m0 + m, gk = k0 + k;
            int phys = pack3 ? (gk + gk / 3) : gk;
            As[k][m] = (gm < M && gk < K) ? (float)A[(size_t)gm * lda + phys] : 0.f;
        }
        if (isf) {
            const float* Wf = (const float*)W;
#pragma unroll
            for (int i = 0; i < 4; ++i) {
                int idx = i * 256 + t;
                int k = idx >> 6, nn = idx & 63;
                int gk = k0 + k;
                Ws[k][nn] = (gk < K) ? Wf[(size_t)gk * N + n0 + nn] : 0.f;
            }
        } else {
            const bf16* Wh = (const bf16*)W;
#pragma unroll
            for (int i = 0; i < 4; ++i) {
                int idx = i * 256 + t;
                int k = idx >> 6, nn = idx & 63;
                int gk = k0 + k;
                Ws[k][nn] = (gk < K) ? b2f(Wh[(size_t)gk * N + n0 + nn]) : 0.f;
            }
        }
        __syncthreads();
#pragma unroll
        for (int kk = 0; kk < 16; ++kk) {
            float a[4], b[4];
#pragma unroll
            for (int i = 0; i < 4; ++i) a[i] = As[kk][tm * 4 + i];
#pragma unroll
            for (int j = 0; j < 4; ++j) b[j] = Ws[kk][tn * 4 + j];
#pragma unroll
            for (int i = 0; i < 4; ++i)
#pragma unroll
                for (int j = 0; j < 4; ++j) acc[i][j] += a[i] * b[j];
        }
        __syncthreads();
    }
#pragma unroll
    for (int i = 0; i < 4; ++i) {
        int gm = m0 + tm * 4 + i;
        if (gm >= M) continue;
#pragma unroll
        for (int j = 0; j < 4; ++j) {
            int gn = n0 + tn * 4 + j;
            size_t ci = (size_t)gm * N + gn;
            float v = acc[i][j];
            if (flags & 4) {
                if (isf) v += ((const float*)bias)[gn];
                else     v += b2f(((const bf16*)bias)[gn]);
            }
            if (flags & 1) v = fmaxf(v, 0.f);
            C[ci] = v;
        }
    }
}

// ---------------- pooling ----------------

__global__ __launch_bounds__(256) void pool_k(const float* __restrict__ in, const int* __restrict__ pcols,
                                              f16* __restrict__ out, int n_out, int C, int ld) {
    int idx = blockIdx.x * 256 + threadIdx.x;
    if (idx >= n_out * C) return;
    int r = idx / C, ch = idx - r * C;
    const int* pc = pcols + (size_t)r * 4;
    float ssum = 0.f;
#pragma unroll
    for (int f = 0; f < 4; ++f) ssum += in[(size_t)pc[f] * C + ch];
    out[(size_t)r * ld + ch] = (f16)(0.25f * ssum);
}

// ---------------- final linear ----------------

__global__ __launch_bounds__(256) void linear10_k(const float* __restrict__ h, const void* __restrict__ lw,
                                                  float* __restrict__ accum, int LIN, const int* __restrict__ flag) {
    int isf = flag[0];
    int c = blockIdx.y;
    int t = threadIdx.x;
    int nvec = LIN >> 3;
    int stride = gridDim.x * 256;
    float p = 0.f;
    const float4* h4 = (const float4*)h;
    if (isf) {
        const float4* lw4 = (const float4*)lw + (size_t)c * (LIN >> 2);
        for (int i = blockIdx.x * 256 + t; i < nvec; i += stride) {
            float4 a0 = h4[2 * i], a1 = h4[2 * i + 1];
            float4 b0 = lw4[2 * i], b1 = lw4[2 * i + 1];
            p += a0.x * b0.x + a0.y * b0.y + a0.z * b0.z + a0.w * b0.w
               + a1.x * b1.x + a1.y * b1.y + a1.z * b1.z + a1.w * b1.w;
        }
    } else {
        const uint4* lwv = (const uint4*)lw + (size_t)c * nvec;
        for (int i = blockIdx.x * 256 + t; i < nvec; i += stride) {
            uint4 w4 = lwv[i];
            float4 a0 = h4[2 * i], a1 = h4[2 * i + 1];
            p += a0.x * blo(w4.x) + a0.y * bhi(w4.x)
               + a0.z * blo(w4.y) + a0.w * bhi(w4.y)
               + a1.x * blo(w4.z) + a1.y * bhi(w4.z)
               + a1.z * blo(w4.w) + a1.w * bhi(w4.w);
        }
    }
    for (int off2 = 32; off2 > 0; off2 >>= 1) p += __shfl_down(p, off2);
    __shared__ float wsum[4];
    int wv = t >> 6, lane = t & 63;
    if (lane == 0) wsum[wv] = p;
    __syncthreads();
    if (t == 0) unsafeAtomicAdd(&accum[c], wsum[0] + wsum[1] + wsum[2] + wsum[3]);
}

__global__ void finalize_k(const float* __restrict__ accum, const void* __restrict__ lb,
                           void* __restrict__ outp, const int* __restrict__ flag) {
    int isf = flag[0];
    int t = threadIdx.x;
    if (t < NCLS) {
        float lbv;
        if (isf) lbv = ((const float*)lb)[t];
        else     lbv = b2f(((const bf16*)lb)[t]);
        float v = accum[t] + lbv;
        if (isf) ((float*)outp)[t] = v;
        else     ((bf16*)outp)[t] = __float2bfloat16(v);
    }
}

__global__ void diag_k(void* __restrict__ outp, float val, const int* __restrict__ flag) {
    int isf = flag[0];
    int t = threadIdx.x;
    if (t < NCLS) {
        if (isf) ((float*)outp)[t] = val;
        else     ((bf16*)outp)[t] = __float2bfloat16(val);
    }
}

// ---------------- orchestration ----------------

extern "C" void kernel_launch(void* const* d_in, const int* in_sizes, int n_in,
                              void* d_out, int out_size, void* d_ws, size_t ws_size,
                              hipStream_t stream) {
    const void* x  = d_in[0];
    const int* ei0 = (const int*)d_in[1];
    const int* ei1 = (const int*)d_in[2];
    const int* ei2 = (const int*)d_in[3];
    const int* pc0 = (const int*)d_in[4];
    const int* pc1 = (const int*)d_in[5];
    const void* w0 = d_in[6];
    const void* b0 = d_in[7];
    const void* w1 = d_in[8];
    const void* b1 = d_in[9];
    const void* w2 = d_in[10];
    const void* b2 = d_in[11];
    const void* lw = d_in[12];
    const void* lb = d_in[13];

    const int E0 = in_sizes[1] / 2, E1 = in_sizes[2] / 2, E2 = in_sizes[3] / 2;

    // ---- workspace layout (~153 MB; ws ~512 MB per harness poison) ----
    char* base = (char*)d_ws;
    size_t off = 0;
    auto alloc = [&](size_t bytes) -> void* {
        void* p = base + off;
        off += (bytes + 255) & ~(size_t)255;
        return p;
    };
    f16*      TxAll = (f16*)alloc((size_t)19200000 * 2);
    float*    OutB  = (float*)alloc((size_t)12800000 * 4);
    int*      colS  = (int*)alloc((size_t)EMAX * 4);
    unsigned* colB  = (unsigned*)alloc((size_t)EMAX * 4);
    int*      cntBB = (int*)alloc((size_t)NBLK * NBUK_MAX * 4);
    f16x4*    G0    = (f16x4*)alloc((size_t)N0 * 8);
    f16x4*    G1    = (f16x4*)alloc((size_t)N0 * 8);
    int*      ptr   = (int*)alloc((size_t)(N0 + 1) * 4);
    float*    dinv  = (float*)alloc((size_t)N0 * 4);
    int*      btot  = (int*)alloc((size_t)NBUK_MAX * 4);
    int*      bbase = (int*)alloc((size_t)NBUK_MAX * 4);
    float*    accum = (float*)alloc(64);
    int*      flag  = (int*)(accum + 16);

    detect_k<<<1, 256, 0, stream>>>((const unsigned int*)x, flag);

    const size_t NEED = 158000000;
    if (ws_size < NEED) {
        diag_k<<<1, 64, 0, stream>>>(d_out, (float)(ws_size >> 20), flag);
        return;
    }

    struct Lvl {
        int n, E, cin, cout;
        const int *rows, *cols;
        const void *w, *b;
        int relu;
    };
    Lvl L[3] = {
        {N0, E0, 3, 64, ei0, ei0 + E0, w0, b0, 1},
        {N1, E1, 64, 128, ei1, ei1 + E1, w1, b1, 1},
        {N2, E2, 128, 256, ei2, ei2 + E2, w2, b2, 0},
    };
    f16x4* G[2] = {G0, G1};

    for (int li = 0; li < 3; ++li) {
        const Lvl& v = L[li];
        int n = v.n, E = v.E, cin = v.cin, cout = v.cout;
        int nbuk = (n + BROWS - 1) >> SB;
        int tile = (E + NBLK - 1) / NBLK;
        int ld = (li == 0) ? 24 : KCH * cin;   // L0 packed: slot stride 4
        int slot = (li == 0) ? 4 : cin;

        // deterministic binned CSR build (writes ptr, dinv, colS)
        binH_k<<<NBLK, 256, 0, stream>>>(v.rows, v.cols, cntBB, nbuk, E, tile);
        scanBB_k<<<nbuk, 256, 0, stream>>>(cntBB, btot, nbuk);
        scanb_k<<<1, 1024, 0, stream>>>(btot, bbase, nbuk, ptr, n);
        binS_k<<<NBLK, 256, 0, stream>>>(v.rows, v.cols, cntBB, bbase, colB, nbuk, E, tile);
        binB_k<<<nbuk, 256, 0, stream>>>(btot, bbase, colB, ptr, dinv, colS, n);

        if (li == 0)
            convert_x_k<<<(N0 + 255) / 256, 256, 0, stream>>>(x, TxAll, G0, dinv, N0, flag);

        // Chebyshev recurrence into fused slots
        for (int k = 1; k < KCH; ++k) {
            float alpha = (k >= 2) ? 2.f : 1.f;
            if (li == 0) {
                prop_narrow_k<<<(n + 7) / 8, 256, 0, stream>>>(ptr, colS, dinv,
                                                               G[(k - 1) & 1], G[k & 1],
                                                               TxAll + (size_t)k * 4, n, alpha, k >= 2);
            } else {
                const f16* hin = TxAll + (size_t)(k - 1) * slot;
                const f16* sub = (k >= 2) ? (TxAll + (size_t)(k - 2) * slot) : nullptr;
                f16* o = TxAll + (size_t)k * slot;
                if (cin == 64)
                    prop_wide2_k<<<(n + 3) / 4, 256, 0, stream>>>(ptr, colS, dinv, hin, sub, o, ld, n, alpha, k >= 2);
                else
                    prop_wide1h_k<<<(n + 3) / 4, 256, 0, stream>>>(ptr, colS, dinv, hin, sub, o, ld, n, alpha, k >= 2);
            }
        }

        // GEMM: OutB[n,cout] = TxAll @ w + bias (+relu)
        dim3 gg(cout / 64, (n + 63) / 64);
        if (li == 0)
            gemm_k<<<gg, 256, 0, stream>>>(TxAll, ld, v.w, v.b, OutB, n, cout, KCH * cin, 4 | 8 | (v.relu ? 1 : 0), flag);
        else
            gemm_mfma_k<<<gg, 256, 0, stream>>>(TxAll, ld, v.w, v.b, OutB, n, cout, KCH * cin, 4 | (v.relu ? 1 : 0), flag);

        // pool into next level's slot0
        if (li == 0)
            pool_k<<<(N1 * 64 + 255) / 256, 256, 0, stream>>>(OutB, pc0, TxAll, N1, 64, KCH * 64);
        else if (li == 1)
            pool_k<<<(N2 * 128 + 255) / 256, 256, 0, stream>>>(OutB, pc1, TxAll, N2, 128, KCH * 128);
    }

    hipMemsetAsync(accum, 0, 64, stream);
    {
        dim3 lg(128, NCLS);
        linear10_k<<<lg, 256, 0, stream>>>(OutB, lw, accum, N2 * 256, flag);
    }
    finalize_k<<<1, 64, 0, stream>>>(accum, lb, d_out, flag);
}